// Round 4
// baseline (397.741 us; speedup 1.0000x reference)
//
#include <hip/hip_runtime.h>
#include <hip/hip_bf16.h>
#include <math.h>

#define B 4
#define C 256
#define H 256
#define Wd 256

// ---------------------------------------------------------------------------
// K1: single pass over x. Per (b,c) plane produces:
//   pool16 (16x16 patch means), xproj16/8/4 (interp-transpose projections),
//   sx = (sum x, sum x^2).
// Wave wg owns rows [64wg,64wg+64), processed as 8 strips of 8 rows. All
// h-segment slot indices are constant per strip (boundaries are multiples
// of 8), so accumulators stay statically indexed with only an 8-deep load
// buffer. sched_barrier(0) per strip caps load hoisting (round-3 spill fix).
// Lane l owns pixels [4l,4l+4): single w-segment per scale, contribution
// (p0-S, S) with S = alpha*p0 + beta*pw. One barrier + LDS merge at the end.
// ---------------------------------------------------------------------------
__global__ __launch_bounds__(256) void poolproj_kernel(
    const float* __restrict__ x,
    float* __restrict__ pool16, float* __restrict__ xp16o,
    float* __restrict__ xp8o, float* __restrict__ xp4o,
    float* __restrict__ sx) {

    __shared__ float M[256][33];

    int bc = blockIdx.x;
    int t = threadIdx.x;
    int wg = t >> 6, l = t & 63;
    bool clipLo = (wg == 0), clipHi = (wg == 3);

    const float4* xp = (const float4*)(x + (size_t)bc * (H * Wd));

    // per-lane w-side constants (alpha, beta of S = alpha*p0 + beta*pw)
    float a16, b16, a8, b8, a4, b4;
    {
        float w0 = 4.f * (float)l + 0.5f;
        float s16v = w0 * 0.0625f - 0.5f;
        if (l <= 1 || l >= 62) { a16 = 0.f; b16 = 0.f; }
        else { a16 = s16v - floorf(s16v); b16 = 0.0625f; }
        float s8v = w0 * 0.03125f - 0.5f;
        if (l <= 3 || l >= 60) { a8 = 0.f; b8 = 0.f; }
        else { a8 = s8v - floorf(s8v); b8 = 0.03125f; }
        float s4v = w0 * 0.015625f - 0.5f;
        if (l <= 7 || l >= 56) { a4 = 0.f; b4 = 0.f; }
        else { a4 = s4v - floorf(s4v); b4 = 0.015625f; }
    }

    float A16L[6] = {0,0,0,0,0,0}, A16H[6] = {0,0,0,0,0,0};
    float A8L[4] = {0,0,0,0},      A8H[4] = {0,0,0,0};
    float A4L[3] = {0,0,0},        A4H[3] = {0,0,0};
    float PP[4] = {0,0,0,0};
    float sx1 = 0.f, sx2 = 0.f;

#pragma unroll
    for (int p = 0; p < 8; ++p) {
        // strip-constant h-segment slots (compile-time under full unroll)
        const int k16 = (p >= 1) ? ((p - 1) >> 1) : -1;
        const int k8  = (p >= 2) ? ((p - 2) >> 2) : -1;
        const int k4  = (p >= 4) ? 0 : -1;

        float4 v[8];
#pragma unroll
        for (int q = 0; q < 8; ++q)
            v[q] = xp[((wg << 6) + p * 8 + q) * 64 + l];

#pragma unroll
        for (int q = 0; q < 8; ++q) {
            const int rr = p * 8 + q;
            float p0 = (v[q].x + v[q].y) + (v[q].z + v[q].w);
            float pw = fmaf(3.f, v[q].w, fmaf(2.f, v[q].z, v[q].y));
            sx1 += p0;
            sx2 += v[q].x * v[q].x + v[q].y * v[q].y +
                   v[q].z * v[q].z + v[q].w * v[q].w;
            PP[rr >> 4] += p0;

            float S16 = fmaf(b16, pw, a16 * p0);
            float S8  = fmaf(b8,  pw, a8  * p0);
            float S4  = fmaf(b4,  pw, a4  * p0);
            float u16 = p0 - S16, u8 = p0 - S8, u4 = p0 - S4;

            // s16 h-weights
            {
                const float fh = ((float)rr + 0.5f) * 0.0625f - 0.5f - (float)k16;
                float wlo = 1.f - fh, whi = fh;
                if (p == 0) { if (clipLo) { wlo = 0.f; whi = 1.f; } }
                if (p == 7) { if (clipHi) { wlo = 1.f; whi = 0.f; } }
                A16L[k16 + 1] += wlo * u16;  A16L[k16 + 2] += whi * u16;
                A16H[k16 + 1] += wlo * S16;  A16H[k16 + 2] += whi * S16;
            }
            // s8
            {
                const float fh = ((float)rr + 0.5f) * 0.03125f - 0.5f - (float)k8;
                float wlo = 1.f - fh, whi = fh;
                if (p < 2)  { if (clipLo) { wlo = 0.f; whi = 1.f; } }
                if (p >= 6) { if (clipHi) { wlo = 1.f; whi = 0.f; } }
                A8L[k8 + 1] += wlo * u8;  A8L[k8 + 2] += whi * u8;
                A8H[k8 + 1] += wlo * S8;  A8H[k8 + 2] += whi * S8;
            }
            // s4
            {
                const float fh = ((float)rr + 0.5f) * 0.015625f - 0.5f - (float)k4;
                float wlo = 1.f - fh, whi = fh;
                if (p < 4)  { if (clipLo) { wlo = 0.f; whi = 1.f; } }
                if (p >= 4) { if (clipHi) { wlo = 1.f; whi = 0.f; } }
                A4L[k4 + 1] += wlo * u4;  A4L[k4 + 2] += whi * u4;
                A4H[k4 + 1] += wlo * S4;  A4H[k4 + 2] += whi * S4;
            }
        }
        __builtin_amdgcn_sched_barrier(0);   // cap load hoisting to one strip
    }

    // dump accumulators to LDS
    {
        float* m = M[t];
#pragma unroll
        for (int q = 0; q < 6; ++q) { m[q] = A16L[q]; m[6 + q] = A16H[q]; }
#pragma unroll
        for (int q = 0; q < 4; ++q) { m[12 + q] = A8L[q]; m[16 + q] = A8H[q]; }
#pragma unroll
        for (int q = 0; q < 3; ++q) { m[20 + q] = A4L[q]; m[23 + q] = A4H[q]; }
#pragma unroll
        for (int q = 0; q < 4; ++q) m[26 + q] = PP[q];
        m[30] = sx1; m[31] = sx2;
    }
    __syncthreads();

    // ---- deterministic merge (byte-identical to validated round-3 code) ----
    {
        int i = t >> 4, j = t & 15;
        float sum = 0.f;
        for (int w2 = 0; w2 < 4; ++w2) {
            int idx = i - 4 * w2 + 1;
            if (idx < 0 || idx > 5) continue;
            int lbeg = (j == 0) ? 0 : 4 * j + 2;
            int lend = (j == 15) ? 64 : 4 * j + 6;
            for (int l2 = lbeg; l2 < lend; ++l2) sum += M[w2 * 64 + l2][idx];
            if (j >= 1) {
                int l2b = (j == 1) ? 0 : 4 * (j - 1) + 2;
                int l2e = 4 * (j - 1) + 6;
                for (int l2 = l2b; l2 < l2e; ++l2) sum += M[w2 * 64 + l2][6 + idx];
            }
        }
        xp16o[(size_t)bc * 256 + t] = sum;
    }
    {
        int i = t >> 4, j = t & 15;
        int w2 = i >> 2, slot = i & 3;
        float sum = M[w2 * 64 + 4 * j][26 + slot] + M[w2 * 64 + 4 * j + 1][26 + slot] +
                    M[w2 * 64 + 4 * j + 2][26 + slot] + M[w2 * 64 + 4 * j + 3][26 + slot];
        pool16[(size_t)bc * 256 + t] = sum * (1.f / 256.f);
    }
    if (t < 64) {
        int i8 = t >> 3, j8 = t & 7;
        float sum = 0.f;
        for (int w2 = 0; w2 < 4; ++w2) {
            int idx = i8 - 2 * w2 + 1;
            if (idx < 0 || idx > 3) continue;
            int lbeg = (j8 == 0) ? 0 : 8 * j8 + 4;
            int lend = (j8 == 7) ? 64 : 8 * j8 + 12;
            for (int l2 = lbeg; l2 < lend; ++l2) sum += M[w2 * 64 + l2][12 + idx];
            if (j8 >= 1) {
                int l2b = (j8 == 1) ? 0 : 8 * (j8 - 1) + 4;
                int l2e = 8 * (j8 - 1) + 12;
                for (int l2 = l2b; l2 < l2e; ++l2) sum += M[w2 * 64 + l2][16 + idx];
            }
        }
        xp8o[(size_t)bc * 64 + t] = sum;
    }
    else if (t < 80) {
        int e = t - 64;
        int i4 = e >> 2, j4 = e & 3;
        float sum = 0.f;
        for (int w2 = 0; w2 < 4; ++w2) {
            int idx = i4 - w2 + 1;
            if (idx < 0 || idx > 2) continue;
            int lbeg = (j4 == 0) ? 0 : 16 * j4 + 8;
            int lend = (j4 == 3) ? 64 : 16 * j4 + 24;
            for (int l2 = lbeg; l2 < lend; ++l2) sum += M[w2 * 64 + l2][20 + idx];
            if (j4 >= 1) {
                int l2b = (j4 == 1) ? 0 : 16 * (j4 - 1) + 8;
                int l2e = 16 * (j4 - 1) + 24;
                for (int l2 = l2b; l2 < l2e; ++l2) sum += M[w2 * 64 + l2][23 + idx];
            }
        }
        xp4o[(size_t)bc * 16 + e] = sum;
    }
    if (t >= 128 && t < 192) {
        int lane = t - 128;
        float s1 = M[lane][30] + M[64 + lane][30] + M[128 + lane][30] + M[192 + lane][30];
        float s2 = M[lane][31] + M[64 + lane][31] + M[128 + lane][31] + M[192 + lane][31];
#pragma unroll
        for (int off = 1; off < 64; off <<= 1) {
            s1 += __shfl_xor(s1, off);
            s2 += __shfl_xor(s2, off);
        }
        if (lane == 0) { sx[bc * 2] = s1; sx[bc * 2 + 1] = s2; }
    }
}

// ---------------------------------------------------------------------------
// K2: per (b, scale, site) attention + channel-mix. (unchanged, validated)
// ---------------------------------------------------------------------------
__global__ __launch_bounds__(256) void site_kernel(
    const float* __restrict__ pool16,
    const float* __restrict__ cw0, const float* __restrict__ cw1,
    const float* __restrict__ cw2,
    const float* __restrict__ sw0, const float* __restrict__ sw1,
    const float* __restrict__ sw2,
    const float* __restrict__ fusion_w,
    float* __restrict__ y4, float* __restrict__ y8, float* __restrict__ y16) {

    __shared__ float P[256];
    __shared__ float Wm[961];
    __shared__ float QKV[279];
    __shared__ float QW[93];
    __shared__ float A[9];
    __shared__ float OUTV[93];

    int t = threadIdx.x;
    int blk = blockIdx.x;
    int b = blk / 336;
    int r = blk % 336;

    int s, site, foff;
    const float* cw; const float* sw; float* yout;
    if (r < 256)      { s = 16; site = r;       cw = cw2; sw = sw2; foff = 186; yout = y16; }
    else if (r < 320) { s = 8;  site = r - 256; cw = cw1; sw = sw1; foff = 93;  yout = y8;  }
    else              { s = 4;  site = r - 320; cw = cw0; sw = sw0; foff = 0;   yout = y4;  }
    int i = site / s, j = site % s;

    for (int idx = t; idx < 961; idx += 256) Wm[idx] = sw[idx];

    {
        int f = 16 / s;
        float acc = 0.f;
        int base = (b * 256 + t) * 256;
        for (int ii = 0; ii < f; ++ii)
            for (int jj = 0; jj < f; ++jj)
                acc += pool16[base + (i * f + ii) * 16 + (j * f + jj)];
        P[t] = acc / (float)(f * f);
    }
    __syncthreads();

    for (int o = t; o < 279; o += 256) {
        const float4* wrow = (const float4*)(cw + o * 256);
        float acc = 0.f;
#pragma unroll 8
        for (int c4 = 0; c4 < 64; ++c4) {
            float4 wv = wrow[c4];
            acc += wv.x * P[c4 * 4] + wv.y * P[c4 * 4 + 1] +
                   wv.z * P[c4 * 4 + 2] + wv.w * P[c4 * 4 + 3];
        }
        QKV[o] = acc;
    }
    __syncthreads();

    if (t < 93) {
        int g = t / 31, m = t % 31;
        float acc = 0.f;
        for (int n = 0; n < 31; ++n) acc += QKV[g * 31 + n] * Wm[n * 31 + m];
        QW[t] = acc;
    }
    __syncthreads();
    if (t < 9) {
        int g = t / 3, h = t % 3;
        float acc = 0.f;
        for (int m = 0; m < 31; ++m) acc += QW[g * 31 + m] * QKV[93 + h * 31 + m];
        A[t] = acc * 0.57735026918962576f;
    }
    __syncthreads();
    if (t < 3) {
        float a0 = A[t * 3], a1 = A[t * 3 + 1], a2 = A[t * 3 + 2];
        float mx = fmaxf(a0, fmaxf(a1, a2));
        float e0 = expf(a0 - mx), e1 = expf(a1 - mx), e2 = expf(a2 - mx);
        float inv = 1.0f / (e0 + e1 + e2);
        A[t * 3] = e0 * inv; A[t * 3 + 1] = e1 * inv; A[t * 3 + 2] = e2 * inv;
    }
    __syncthreads();
    if (t < 93) {
        int g = t / 31, n = t % 31;
        OUTV[t] = A[g * 3] * QKV[186 + n] + A[g * 3 + 1] * QKV[186 + 31 + n] +
                  A[g * 3 + 2] * QKV[186 + 62 + n];
    }
    __syncthreads();
    {
        const float* fr = fusion_w + t * 279 + foff;
        float acc = 0.f;
#pragma unroll 31
        for (int c = 0; c < 93; ++c) acc += fr[c] * OUTV[c];
        yout[(size_t)(b * 256 + t) * (s * s) + site] = acc;
    }
}

// ---------------------------------------------------------------------------
// K3: GroupNorm stats WITHOUT touching x. (unchanged, validated)
// ---------------------------------------------------------------------------
__global__ __launch_bounds__(256) void groupstats_kernel(
    const float* __restrict__ y4, const float* __restrict__ y8,
    const float* __restrict__ y16,
    const float* __restrict__ xp4, const float* __restrict__ xp8,
    const float* __restrict__ xp16,
    const float* __restrict__ sx, const float* __restrict__ fusion_b,
    float* __restrict__ stats_g) {

    __shared__ float G1616[256], G168[128], G164[64], G88[64], G84[32], G44[16];
    __shared__ float cs[28];
    __shared__ float ybuf[336], xbuf[336];
    __shared__ float Tm[256];
    __shared__ float red[8];

    int t = threadIdx.x;
    int bg = blockIdx.x;
    int b = bg >> 5, g = bg & 31;

    for (int e = t; e < 588; e += 256) {
        if (e >= 560) {
            int q = e - 560; int sC, iC;
            if (q < 16) { sC = 16; iC = q; }
            else if (q < 24) { sC = 8; iC = q - 16; }
            else { sC = 4; iC = q - 24; }
            int R = 256 / sC;
            int lo = max(0, R * iC - R / 2), hi = min(256, R * iC + (3 * R) / 2);
            float Rinv = 1.f / (float)R, smax = (float)(sC - 1);
            float a = 0.f;
            for (int h = lo; h < hi; ++h) {
                float src = fminf(fmaxf(((float)h + 0.5f) * Rinv - 0.5f, 0.f), smax);
                int lq = (int)src; float fr = src - (float)lq;
                a += (iC == lq) ? (1.f - fr) : ((iC == lq + 1) ? fr : 0.f);
            }
            cs[q] = a;
            continue;
        }
        int sA, sB, iA, iB; float* dst; int off;
        if (e < 256)      { sA = 16; sB = 16; iA = e >> 4; iB = e & 15; dst = G1616; off = e; }
        else if (e < 384) { int q = e - 256; sA = 16; sB = 8; iA = q >> 3; iB = q & 7; dst = G168; off = q; }
        else if (e < 448) { int q = e - 384; sA = 16; sB = 4; iA = q >> 2; iB = q & 3; dst = G164; off = q; }
        else if (e < 512) { int q = e - 448; sA = 8;  sB = 8; iA = q >> 3; iB = q & 7; dst = G88;  off = q; }
        else if (e < 544) { int q = e - 512; sA = 8;  sB = 4; iA = q >> 2; iB = q & 3; dst = G84;  off = q; }
        else              { int q = e - 544; sA = 4;  sB = 4; iA = q >> 2; iB = q & 3; dst = G44;  off = q; }
        int RA = 256 / sA, RB = 256 / sB;
        int lo = max(max(0, RA * iA - RA / 2), RB * iB - RB / 2);
        int hi = min(min(256, RA * iA + (3 * RA) / 2), RB * iB + (3 * RB) / 2);
        float RAi = 1.f / (float)RA, RBi = 1.f / (float)RB;
        float smA = (float)(sA - 1), smB = (float)(sB - 1);
        float a = 0.f;
        for (int h = lo; h < hi; ++h) {
            float sa = fminf(fmaxf(((float)h + 0.5f) * RAi - 0.5f, 0.f), smA);
            int la = (int)sa; float fa = sa - (float)la;
            float wa = (iA == la) ? (1.f - fa) : ((iA == la + 1) ? fa : 0.f);
            float sb = fminf(fmaxf(((float)h + 0.5f) * RBi - 0.5f, 0.f), smB);
            int lb = (int)sb; float fb_ = sb - (float)lb;
            float wb = (iB == lb) ? (1.f - fb_) : ((iB == lb + 1) ? fb_ : 0.f);
            a += wa * wb;
        }
        dst[off] = a;
    }
    __syncthreads();

    double gS1 = 0.0, gS2 = 0.0;

    for (int c8 = 0; c8 < 8; ++c8) {
        int c = g * 8 + c8;
        size_t bc = (size_t)(b * 256 + c);
        ybuf[t] = y16[bc * 256 + t];
        xbuf[t] = xp16[bc * 256 + t];
        if (t < 64) { ybuf[256 + t] = y8[bc * 64 + t]; xbuf[256 + t] = xp8[bc * 64 + t]; }
        else if (t < 80) { ybuf[256 + t] = y4[bc * 16 + (t - 64)]; xbuf[256 + t] = xp4[bc * 16 + (t - 64)]; }
        __syncthreads();

        float pu = 0.f, pv = 0.f;
        for (int e = t; e < 336; e += 256) {
            float yv = ybuf[e];
            pv += 2.f * yv * xbuf[e];
            int ci, cj;
            if (e < 256)      { ci = e >> 4;               cj = e & 15; }
            else if (e < 320) { ci = 16 + ((e - 256) >> 3); cj = 16 + ((e - 256) & 7); }
            else              { ci = 24 + ((e - 320) >> 2); cj = 24 + ((e - 320) & 3); }
            pu += yv * cs[ci] * cs[cj];
        }

        for (int p = 0; p < 6; ++p) {
            const float* Gp; int sA, sB, yAoff, yBoff; float factor;
            switch (p) {
                case 0: Gp = G1616; sA = 16; sB = 16; yAoff = 0;   yBoff = 0;   factor = 1.f; break;
                case 1: Gp = G168;  sA = 16; sB = 8;  yAoff = 0;   yBoff = 256; factor = 2.f; break;
                case 2: Gp = G164;  sA = 16; sB = 4;  yAoff = 0;   yBoff = 320; factor = 2.f; break;
                case 3: Gp = G88;   sA = 8;  sB = 8;  yAoff = 256; yBoff = 256; factor = 1.f; break;
                case 4: Gp = G84;   sA = 8;  sB = 4;  yAoff = 256; yBoff = 320; factor = 2.f; break;
                default:Gp = G44;   sA = 4;  sB = 4;  yAoff = 320; yBoff = 320; factor = 1.f; break;
            }
            __syncthreads();
            int nT = sB * sA;
            if (t < nT) {
                int iB = t / sA, jA = t - iB * sA;
                float a = 0.f;
                for (int jB = 0; jB < sB; ++jB)
                    a += Gp[jA * sB + jB] * ybuf[yBoff + iB * sB + jB];
                Tm[t] = a;
            }
            __syncthreads();
            int nB = sA * sA;
            if (t < nB) {
                int iA = t / sA, jA = t - iA * sA;
                float a = 0.f;
                for (int iB = 0; iB < sB; ++iB)
                    a += Gp[iA * sB + iB] * Tm[iB * sA + jA];
                pv += factor * ybuf[yAoff + t] * a;
            }
        }

#pragma unroll
        for (int off = 1; off < 64; off <<= 1) {
            pu += __shfl_xor(pu, off);
            pv += __shfl_xor(pv, off);
        }
        __syncthreads();
        if ((t & 63) == 0) { red[(t >> 6) * 2] = pu; red[(t >> 6) * 2 + 1] = pv; }
        __syncthreads();
        if (t == 0) {
            float puT = red[0] + red[2] + red[4] + red[6];
            float pvT = red[1] + red[3] + red[5] + red[7];
            float fb = fusion_b[c];
            float s1 = sx[(b * 256 + c) * 2], s2 = sx[(b * 256 + c) * 2 + 1];
            double S1 = (double)s1 + 65536.0 * (double)fb + (double)puT;
            double S2 = (double)s2 + 2.0 * (double)fb * (double)s1 +
                        65536.0 * (double)fb * (double)fb +
                        2.0 * (double)fb * (double)puT + (double)pvT;
            gS1 += S1; gS2 += S2;
        }
        __syncthreads();
    }

    if (t == 0) {
        double mean = gS1 / 524288.0;
        double var  = gS2 / 524288.0 - mean * mean;
        stats_g[bg * 2] = (float)mean;
        stats_g[bg * 2 + 1] = (float)(1.0 / sqrt(var + 1e-5));
    }
}

// ---------------------------------------------------------------------------
// K4: final pass — recompute f via LDS-blended interp, normalize, write.
// (unchanged, validated)
// ---------------------------------------------------------------------------
__global__ __launch_bounds__(256) void write_kernel(
    const float* __restrict__ x,
    const float* __restrict__ ws_y4, const float* __restrict__ ws_y8,
    const float* __restrict__ ws_y16,
    const float* __restrict__ fusion_b,
    const float* __restrict__ gn_w, const float* __restrict__ gn_b,
    const float* __restrict__ stats_g,
    float* __restrict__ out) {

    __shared__ float ly16[256], ly8[64], ly4[16];
    __shared__ float2 rbd16[16][16];
    __shared__ float2 rbd8[16][8];
    __shared__ float2 rbd4[16][4];

    int blk = blockIdx.x;
    int hblk = blk & 15;
    int c = (blk >> 4) & 255;
    int b = blk >> 12;
    int t = threadIdx.x;

    ly16[t] = ws_y16[(size_t)(b * 256 + c) * 256 + t];
    if (t < 64) ly8[t] = ws_y8[(size_t)(b * 256 + c) * 64 + t];
    if (t < 16) ly4[t] = ws_y4[(size_t)(b * 256 + c) * 16 + t];
    __syncthreads();

    for (int idx = t; idx < 448; idx += 256) {
        int r = idx / 28;
        int q = idx - r * 28;
        int h = hblk * 16 + r;
        if (q < 16) {
            float src = (h + 0.5f) * 0.0625f - 0.5f;
            src = fminf(fmaxf(src, 0.f), 15.f);
            int lo = (int)src; float wf = src - lo; int hi = min(lo + 1, 15);
            float rb = (1.f - wf) * ly16[lo * 16 + q] + wf * ly16[hi * 16 + q];
            rbd16[r][q].x = rb;
            if (q > 0) rbd16[r][q - 1].y = rb;
            if (q == 15) rbd16[r][15].y = rb;
        } else if (q < 24) {
            int jj = q - 16;
            float src = (h + 0.5f) * 0.03125f - 0.5f;
            src = fminf(fmaxf(src, 0.f), 7.f);
            int lo = (int)src; float wf = src - lo; int hi = min(lo + 1, 7);
            float rb = (1.f - wf) * ly8[lo * 8 + jj] + wf * ly8[hi * 8 + jj];
            rbd8[r][jj].x = rb;
            if (jj > 0) rbd8[r][jj - 1].y = rb;
            if (jj == 7) rbd8[r][7].y = rb;
        } else {
            int jj = q - 24;
            float src = (h + 0.5f) * 0.015625f - 0.5f;
            src = fminf(fmaxf(src, 0.f), 3.f);
            int lo = (int)src; float wf = src - lo; int hi = min(lo + 1, 3);
            float rb = (1.f - wf) * ly4[lo * 4 + jj] + wf * ly4[hi * 4 + jj];
            rbd4[r][jj].x = rb;
            if (jj > 0) rbd4[r][jj - 1].y = rb;
            if (jj == 3) rbd4[r][3].y = rb;
        }
    }
    __syncthreads();

    int w4 = t & 63;
    int wg = t >> 6;
    int w0 = w4 * 4;

    int jlo16[4], jlo8[4], jlo4[4];
    float ww16[4], ww8[4], ww4[4];
#pragma unroll
    for (int p = 0; p < 4; ++p) {
        int w = w0 + p;
        float s16 = fminf(fmaxf((w + 0.5f) * 0.0625f - 0.5f, 0.f), 15.f);
        jlo16[p] = (int)s16; ww16[p] = s16 - jlo16[p];
        float s8 = fminf(fmaxf((w + 0.5f) * 0.03125f - 0.5f, 0.f), 7.f);
        jlo8[p] = (int)s8; ww8[p] = s8 - jlo8[p];
        float s4 = fminf(fmaxf((w + 0.5f) * 0.015625f - 0.5f, 0.f), 3.f);
        jlo4[p] = (int)s4; ww4[p] = s4 - jlo4[p];
    }

    float fb_c = fusion_b[c];
    int gidx = c >> 3;
    float mean = stats_g[(b * 32 + gidx) * 2];
    float rstd = stats_g[(b * 32 + gidx) * 2 + 1];
    float gwc = gn_w[c], gbc = gn_b[c];

    const float4* xp = (const float4*)(x + (size_t)(b * 256 + c) * (H * Wd));
    float4* op = (float4*)(out + (size_t)(b * 256 + c) * (H * Wd));

#pragma unroll
    for (int it = 0; it < 4; ++it) {
        int r = it * 4 + wg;
        int idx4 = (hblk * 16 + r) * 64 + w4;
        float4 xv = xp[idx4];
        float res[4];
        float px[4] = {xv.x, xv.y, xv.z, xv.w};
#pragma unroll
        for (int p = 0; p < 4; ++p) {
            float f = fb_c;
            float2 v16 = rbd16[r][jlo16[p]];
            f += (1.f - ww16[p]) * v16.x + ww16[p] * v16.y;
            float2 v8 = rbd8[r][jlo8[p]];
            f += (1.f - ww8[p]) * v8.x + ww8[p] * v8.y;
            float2 v4 = rbd4[r][jlo4[p]];
            f += (1.f - ww4[p]) * v4.x + ww4[p] * v4.y;
            float tv = px[p] + f;
            res[p] = (tv - mean) * rstd * gwc + gbc;
        }
        op[idx4] = make_float4(res[0], res[1], res[2], res[3]);
    }
}

// ---------------------------------------------------------------------------
extern "C" void kernel_launch(void* const* d_in, const int* in_sizes, int n_in,
                              void* d_out, int out_size, void* d_ws, size_t ws_size,
                              hipStream_t stream) {
    const float* x   = (const float*)d_in[0];
    const float* cw0 = (const float*)d_in[1];
    const float* cw1 = (const float*)d_in[2];
    const float* cw2 = (const float*)d_in[3];
    const float* sw0 = (const float*)d_in[4];
    const float* sw1 = (const float*)d_in[5];
    const float* sw2 = (const float*)d_in[6];
    const float* fw  = (const float*)d_in[7];
    const float* fb  = (const float*)d_in[8];
    const float* gw  = (const float*)d_in[9];
    const float* gb  = (const float*)d_in[10];
    float* out = (float*)d_out;

    float* ws     = (float*)d_ws;
    float* pool16 = ws;                    // 262144
    float* y4     = pool16 + 262144;       // 16384
    float* y8     = y4 + 16384;            // 65536
    float* y16    = y8 + 65536;            // 262144
    float* xp16   = y16 + 262144;          // 262144
    float* xp8    = xp16 + 262144;         // 65536
    float* xp4    = xp8 + 65536;           // 16384
    float* sx     = xp4 + 16384;           // 2048
    float* statsg = sx + 2048;             // 256

    poolproj_kernel<<<B * C, 256, 0, stream>>>(x, pool16, xp16, xp8, xp4, sx);
    site_kernel<<<B * 336, 256, 0, stream>>>(pool16, cw0, cw1, cw2,
                                             sw0, sw1, sw2, fw, y4, y8, y16);
    groupstats_kernel<<<B * 32, 256, 0, stream>>>(y4, y8, y16, xp4, xp8, xp16,
                                                  sx, fb, statsg);
    write_kernel<<<B * C * 16, 256, 0, stream>>>(x, y4, y8, y16, fb, gw, gb,
                                                 statsg, out);
}

// Round 5
// 317.909 us; speedup vs baseline: 1.2511x; 1.2511x over previous
//
#include <hip/hip_runtime.h>
#include <hip/hip_bf16.h>
#include <math.h>

#define B 4
#define C 256
#define H 256
#define Wd 256

// ---------------------------------------------------------------------------
// K1 (stage A): streaming x pass. Block = (plane, 16-row slab). 16384 blocks.
// Per row, lane l (pixels 4l..4l+3) computes for each scale the pair
// (u = p0-S, S) with S = alpha*p0 + beta*pw (single w-segment per lane,
// validated rounds 1-4), dumps 7 floats to LDS; after ONE barrier, 464
// column-reduce tasks emit R rowproj entries (28/row), pool16 (this slab is
// exactly one patch row), and per-slab sx partials. Tiny register state.
// ---------------------------------------------------------------------------
__global__ __launch_bounds__(256) void xread_kernel(
    const float* __restrict__ x,
    float* __restrict__ pool16,     // [1024][256]
    float* __restrict__ Rbuf,       // [1024][256][28]
    float* __restrict__ sxpart) {   // [16384][2]

    __shared__ float S[16][8][66];  // [row][slot][lane(+pad)]
    __shared__ float rs[4][2];

    int blk = blockIdx.x;
    int slab = blk & 15;
    int bc = blk >> 4;
    int t = threadIdx.x;
    int wg = t >> 6, l = t & 63;

    const float4* xp = (const float4*)(x + (size_t)bc * (H * Wd));

    // per-lane w-side constants (validated)
    float a16, b16, a8, b8, a4, b4;
    {
        float w0 = 4.f * (float)l + 0.5f;
        float s16v = w0 * 0.0625f - 0.5f;
        if (l <= 1 || l >= 62) { a16 = 0.f; b16 = 0.f; }
        else { a16 = s16v - floorf(s16v); b16 = 0.0625f; }
        float s8v = w0 * 0.03125f - 0.5f;
        if (l <= 3 || l >= 60) { a8 = 0.f; b8 = 0.f; }
        else { a8 = s8v - floorf(s8v); b8 = 0.03125f; }
        float s4v = w0 * 0.015625f - 0.5f;
        if (l <= 7 || l >= 56) { a4 = 0.f; b4 = 0.f; }
        else { a4 = s4v - floorf(s4v); b4 = 0.015625f; }
    }

    float sx1 = 0.f, sx2 = 0.f;
    float4 v[4];
#pragma unroll
    for (int it = 0; it < 4; ++it)
        v[it] = xp[(slab * 16 + wg * 4 + it) * 64 + l];

#pragma unroll
    for (int it = 0; it < 4; ++it) {
        int r = wg * 4 + it;
        float4 vv = v[it];
        float p0 = (vv.x + vv.y) + (vv.z + vv.w);
        float pw = fmaf(3.f, vv.w, fmaf(2.f, vv.z, vv.y));
        sx1 += p0;
        sx2 += vv.x * vv.x + vv.y * vv.y + vv.z * vv.z + vv.w * vv.w;
        float S16 = fmaf(b16, pw, a16 * p0);
        float S8  = fmaf(b8,  pw, a8  * p0);
        float S4  = fmaf(b4,  pw, a4  * p0);
        S[r][0][l] = p0 - S16;  S[r][1][l] = S16;
        S[r][2][l] = p0 - S8;   S[r][3][l] = S8;
        S[r][4][l] = p0 - S4;   S[r][5][l] = S4;
        S[r][6][l] = p0;
    }

    // per-wave sx reduce (validated pattern)
#pragma unroll
    for (int off = 1; off < 64; off <<= 1) {
        sx1 += __shfl_xor(sx1, off);
        sx2 += __shfl_xor(sx2, off);
    }
    if (l == 0) { rs[wg][0] = sx1; rs[wg][1] = sx2; }
    __syncthreads();

    // column-reduce tasks: 448 rowproj + 16 pool
    for (int tk = t; tk < 464; tk += 256) {
        if (tk < 448) {
            int r = tk / 28, col = tk - (tk / 28) * 28;
            int j, uslot, lbegU, lendU, lbegS, lendS;
            if (col < 16) {
                j = col; uslot = 0;
                lbegU = (j == 0) ? 0 : 4 * j + 2;
                lendU = (j == 15) ? 64 : 4 * j + 6;
                if (j >= 1) { lbegS = (j == 1) ? 0 : 4 * (j - 1) + 2; lendS = 4 * (j - 1) + 6; }
                else { lbegS = 0; lendS = 0; }
            } else if (col < 24) {
                j = col - 16; uslot = 2;
                lbegU = (j == 0) ? 0 : 8 * j + 4;
                lendU = (j == 7) ? 64 : 8 * j + 12;
                if (j >= 1) { lbegS = (j == 1) ? 0 : 8 * (j - 1) + 4; lendS = 8 * (j - 1) + 12; }
                else { lbegS = 0; lendS = 0; }
            } else {
                j = col - 24; uslot = 4;
                lbegU = (j == 0) ? 0 : 16 * j + 8;
                lendU = (j == 3) ? 64 : 16 * j + 24;
                if (j >= 1) { lbegS = (j == 1) ? 0 : 16 * (j - 1) + 8; lendS = 16 * (j - 1) + 24; }
                else { lbegS = 0; lendS = 0; }
            }
            float sum = 0.f;
            for (int l2 = lbegU; l2 < lendU; ++l2) sum += S[r][uslot][l2];
            for (int l2 = lbegS; l2 < lendS; ++l2) sum += S[r][uslot + 1][l2];
            Rbuf[((size_t)bc * 256 + slab * 16 + r) * 28 + col] = sum;
        } else {
            int j = tk - 448;
            float sum = 0.f;
            for (int r2 = 0; r2 < 16; ++r2) {
                sum += S[r2][6][4 * j] + S[r2][6][4 * j + 1] +
                       S[r2][6][4 * j + 2] + S[r2][6][4 * j + 3];
            }
            pool16[(size_t)bc * 256 + slab * 16 + j] = sum * (1.f / 256.f);
        }
    }
    if (t == 0) {
        sxpart[(size_t)blk * 2]     = rs[0][0] + rs[1][0] + rs[2][0] + rs[3][0];
        sxpart[(size_t)blk * 2 + 1] = rs[0][1] + rs[1][1] + rs[2][1] + rs[3][1];
    }
}

// ---------------------------------------------------------------------------
// K2 (stage B): fold R rowproj with h-interp weights -> xproj16/8/4; fold
// sx partials. One block per plane (1024 blocks).
// ---------------------------------------------------------------------------
__global__ __launch_bounds__(256) void proj_kernel(
    const float* __restrict__ Rbuf, const float* __restrict__ sxpart,
    float* __restrict__ xp16o, float* __restrict__ xp8o,
    float* __restrict__ xp4o, float* __restrict__ sx) {

    __shared__ float Rl[256 * 29];   // padded stride 29

    int bc = blockIdx.x;
    int t = threadIdx.x;

    const float* rp = Rbuf + (size_t)bc * 7168;
    for (int e = t; e < 7168; e += 256) {
        int r = e / 28, c = e - r * 28;
        Rl[r * 29 + c] = rp[e];
    }
    __syncthreads();

    // s16: thread t -> (i=t>>4, j=t&15)
    {
        int i = t >> 4, j = t & 15;
        float acc = 0.f;
        int r0 = max(0, 16 * i - 8), r1 = min(255, 16 * i + 23);
        for (int r = r0; r <= r1; ++r) {
            float src = fminf(fmaxf(((float)r + 0.5f) * 0.0625f - 0.5f, 0.f), 15.f);
            int lo = (int)src; float fr = src - (float)lo;
            float w = (i == lo) ? (1.f - fr) : ((i == lo + 1) ? fr : 0.f);
            acc += w * Rl[r * 29 + j];
        }
        xp16o[(size_t)bc * 256 + t] = acc;
    }
    if (t < 64) {
        int i = t >> 3, j = t & 7;
        float acc = 0.f;
        int r0 = max(0, 32 * i - 16), r1 = min(255, 32 * i + 47);
        for (int r = r0; r <= r1; ++r) {
            float src = fminf(fmaxf(((float)r + 0.5f) * 0.03125f - 0.5f, 0.f), 7.f);
            int lo = (int)src; float fr = src - (float)lo;
            float w = (i == lo) ? (1.f - fr) : ((i == lo + 1) ? fr : 0.f);
            acc += w * Rl[r * 29 + 16 + j];
        }
        xp8o[(size_t)bc * 64 + t] = acc;
    } else if (t < 80) {
        int e = t - 64;
        int i = e >> 2, j = e & 3;
        float acc = 0.f;
        int r0 = max(0, 64 * i - 32), r1 = min(255, 64 * i + 95);
        for (int r = r0; r <= r1; ++r) {
            float src = fminf(fmaxf(((float)r + 0.5f) * 0.015625f - 0.5f, 0.f), 3.f);
            int lo = (int)src; float fr = src - (float)lo;
            float w = (i == lo) ? (1.f - fr) : ((i == lo + 1) ? fr : 0.f);
            acc += w * Rl[r * 29 + 24 + j];
        }
        xp4o[(size_t)bc * 16 + e] = acc;
    } else if (t == 128) {
        float s1 = 0.f, s2 = 0.f;
        for (int k = 0; k < 16; ++k) {
            s1 += sxpart[(size_t)(bc * 16 + k) * 2];
            s2 += sxpart[(size_t)(bc * 16 + k) * 2 + 1];
        }
        sx[bc * 2] = s1; sx[bc * 2 + 1] = s2;
    }
}

// ---------------------------------------------------------------------------
// K3: per (b, scale, site) attention + channel-mix. (unchanged, validated)
// ---------------------------------------------------------------------------
__global__ __launch_bounds__(256) void site_kernel(
    const float* __restrict__ pool16,
    const float* __restrict__ cw0, const float* __restrict__ cw1,
    const float* __restrict__ cw2,
    const float* __restrict__ sw0, const float* __restrict__ sw1,
    const float* __restrict__ sw2,
    const float* __restrict__ fusion_w,
    float* __restrict__ y4, float* __restrict__ y8, float* __restrict__ y16) {

    __shared__ float P[256];
    __shared__ float Wm[961];
    __shared__ float QKV[279];
    __shared__ float QW[93];
    __shared__ float A[9];
    __shared__ float OUTV[93];

    int t = threadIdx.x;
    int blk = blockIdx.x;
    int b = blk / 336;
    int r = blk % 336;

    int s, site, foff;
    const float* cw; const float* sw; float* yout;
    if (r < 256)      { s = 16; site = r;       cw = cw2; sw = sw2; foff = 186; yout = y16; }
    else if (r < 320) { s = 8;  site = r - 256; cw = cw1; sw = sw1; foff = 93;  yout = y8;  }
    else              { s = 4;  site = r - 320; cw = cw0; sw = sw0; foff = 0;   yout = y4;  }
    int i = site / s, j = site % s;

    for (int idx = t; idx < 961; idx += 256) Wm[idx] = sw[idx];

    {
        int f = 16 / s;
        float acc = 0.f;
        int base = (b * 256 + t) * 256;
        for (int ii = 0; ii < f; ++ii)
            for (int jj = 0; jj < f; ++jj)
                acc += pool16[base + (i * f + ii) * 16 + (j * f + jj)];
        P[t] = acc / (float)(f * f);
    }
    __syncthreads();

    for (int o = t; o < 279; o += 256) {
        const float4* wrow = (const float4*)(cw + o * 256);
        float acc = 0.f;
#pragma unroll 8
        for (int c4 = 0; c4 < 64; ++c4) {
            float4 wv = wrow[c4];
            acc += wv.x * P[c4 * 4] + wv.y * P[c4 * 4 + 1] +
                   wv.z * P[c4 * 4 + 2] + wv.w * P[c4 * 4 + 3];
        }
        QKV[o] = acc;
    }
    __syncthreads();

    if (t < 93) {
        int g = t / 31, m = t % 31;
        float acc = 0.f;
        for (int n = 0; n < 31; ++n) acc += QKV[g * 31 + n] * Wm[n * 31 + m];
        QW[t] = acc;
    }
    __syncthreads();
    if (t < 9) {
        int g = t / 3, h = t % 3;
        float acc = 0.f;
        for (int m = 0; m < 31; ++m) acc += QW[g * 31 + m] * QKV[93 + h * 31 + m];
        A[t] = acc * 0.57735026918962576f;
    }
    __syncthreads();
    if (t < 3) {
        float a0 = A[t * 3], a1 = A[t * 3 + 1], a2 = A[t * 3 + 2];
        float mx = fmaxf(a0, fmaxf(a1, a2));
        float e0 = expf(a0 - mx), e1 = expf(a1 - mx), e2 = expf(a2 - mx);
        float inv = 1.0f / (e0 + e1 + e2);
        A[t * 3] = e0 * inv; A[t * 3 + 1] = e1 * inv; A[t * 3 + 2] = e2 * inv;
    }
    __syncthreads();
    if (t < 93) {
        int g = t / 31, n = t % 31;
        OUTV[t] = A[g * 3] * QKV[186 + n] + A[g * 3 + 1] * QKV[186 + 31 + n] +
                  A[g * 3 + 2] * QKV[186 + 62 + n];
    }
    __syncthreads();
    {
        const float* fr = fusion_w + t * 279 + foff;
        float acc = 0.f;
#pragma unroll 31
        for (int c = 0; c < 93; ++c) acc += fr[c] * OUTV[c];
        yout[(size_t)(b * 256 + t) * (s * s) + site] = acc;
    }
}

// ---------------------------------------------------------------------------
// K4: GroupNorm stats WITHOUT touching x. (unchanged, validated)
// ---------------------------------------------------------------------------
__global__ __launch_bounds__(256) void groupstats_kernel(
    const float* __restrict__ y4, const float* __restrict__ y8,
    const float* __restrict__ y16,
    const float* __restrict__ xp4, const float* __restrict__ xp8,
    const float* __restrict__ xp16,
    const float* __restrict__ sx, const float* __restrict__ fusion_b,
    float* __restrict__ stats_g) {

    __shared__ float G1616[256], G168[128], G164[64], G88[64], G84[32], G44[16];
    __shared__ float cs[28];
    __shared__ float ybuf[336], xbuf[336];
    __shared__ float Tm[256];
    __shared__ float red[8];

    int t = threadIdx.x;
    int bg = blockIdx.x;
    int b = bg >> 5, g = bg & 31;

    for (int e = t; e < 588; e += 256) {
        if (e >= 560) {
            int q = e - 560; int sC, iC;
            if (q < 16) { sC = 16; iC = q; }
            else if (q < 24) { sC = 8; iC = q - 16; }
            else { sC = 4; iC = q - 24; }
            int R = 256 / sC;
            int lo = max(0, R * iC - R / 2), hi = min(256, R * iC + (3 * R) / 2);
            float Rinv = 1.f / (float)R, smax = (float)(sC - 1);
            float a = 0.f;
            for (int h = lo; h < hi; ++h) {
                float src = fminf(fmaxf(((float)h + 0.5f) * Rinv - 0.5f, 0.f), smax);
                int lq = (int)src; float fr = src - (float)lq;
                a += (iC == lq) ? (1.f - fr) : ((iC == lq + 1) ? fr : 0.f);
            }
            cs[q] = a;
            continue;
        }
        int sA, sB, iA, iB; float* dst; int off;
        if (e < 256)      { sA = 16; sB = 16; iA = e >> 4; iB = e & 15; dst = G1616; off = e; }
        else if (e < 384) { int q = e - 256; sA = 16; sB = 8; iA = q >> 3; iB = q & 7; dst = G168; off = q; }
        else if (e < 448) { int q = e - 384; sA = 16; sB = 4; iA = q >> 2; iB = q & 3; dst = G164; off = q; }
        else if (e < 512) { int q = e - 448; sA = 8;  sB = 8; iA = q >> 3; iB = q & 7; dst = G88;  off = q; }
        else if (e < 544) { int q = e - 512; sA = 8;  sB = 4; iA = q >> 2; iB = q & 3; dst = G84;  off = q; }
        else              { int q = e - 544; sA = 4;  sB = 4; iA = q >> 2; iB = q & 3; dst = G44;  off = q; }
        int RA = 256 / sA, RB = 256 / sB;
        int lo = max(max(0, RA * iA - RA / 2), RB * iB - RB / 2);
        int hi = min(min(256, RA * iA + (3 * RA) / 2), RB * iB + (3 * RB) / 2);
        float RAi = 1.f / (float)RA, RBi = 1.f / (float)RB;
        float smA = (float)(sA - 1), smB = (float)(sB - 1);
        float a = 0.f;
        for (int h = lo; h < hi; ++h) {
            float sa = fminf(fmaxf(((float)h + 0.5f) * RAi - 0.5f, 0.f), smA);
            int la = (int)sa; float fa = sa - (float)la;
            float wa = (iA == la) ? (1.f - fa) : ((iA == la + 1) ? fa : 0.f);
            float sb = fminf(fmaxf(((float)h + 0.5f) * RBi - 0.5f, 0.f), smB);
            int lb = (int)sb; float fb_ = sb - (float)lb;
            float wb = (iB == lb) ? (1.f - fb_) : ((iB == lb + 1) ? fb_ : 0.f);
            a += wa * wb;
        }
        dst[off] = a;
    }
    __syncthreads();

    double gS1 = 0.0, gS2 = 0.0;

    for (int c8 = 0; c8 < 8; ++c8) {
        int c = g * 8 + c8;
        size_t bc = (size_t)(b * 256 + c);
        ybuf[t] = y16[bc * 256 + t];
        xbuf[t] = xp16[bc * 256 + t];
        if (t < 64) { ybuf[256 + t] = y8[bc * 64 + t]; xbuf[256 + t] = xp8[bc * 64 + t]; }
        else if (t < 80) { ybuf[256 + t] = y4[bc * 16 + (t - 64)]; xbuf[256 + t] = xp4[bc * 16 + (t - 64)]; }
        __syncthreads();

        float pu = 0.f, pv = 0.f;
        for (int e = t; e < 336; e += 256) {
            float yv = ybuf[e];
            pv += 2.f * yv * xbuf[e];
            int ci, cj;
            if (e < 256)      { ci = e >> 4;               cj = e & 15; }
            else if (e < 320) { ci = 16 + ((e - 256) >> 3); cj = 16 + ((e - 256) & 7); }
            else              { ci = 24 + ((e - 320) >> 2); cj = 24 + ((e - 320) & 3); }
            pu += yv * cs[ci] * cs[cj];
        }

        for (int p = 0; p < 6; ++p) {
            const float* Gp; int sA, sB, yAoff, yBoff; float factor;
            switch (p) {
                case 0: Gp = G1616; sA = 16; sB = 16; yAoff = 0;   yBoff = 0;   factor = 1.f; break;
                case 1: Gp = G168;  sA = 16; sB = 8;  yAoff = 0;   yBoff = 256; factor = 2.f; break;
                case 2: Gp = G164;  sA = 16; sB = 4;  yAoff = 0;   yBoff = 320; factor = 2.f; break;
                case 3: Gp = G88;   sA = 8;  sB = 8;  yAoff = 256; yBoff = 256; factor = 1.f; break;
                case 4: Gp = G84;   sA = 8;  sB = 4;  yAoff = 256; yBoff = 320; factor = 2.f; break;
                default:Gp = G44;   sA = 4;  sB = 4;  yAoff = 320; yBoff = 320; factor = 1.f; break;
            }
            __syncthreads();
            int nT = sB * sA;
            if (t < nT) {
                int iB = t / sA, jA = t - iB * sA;
                float a = 0.f;
                for (int jB = 0; jB < sB; ++jB)
                    a += Gp[jA * sB + jB] * ybuf[yBoff + iB * sB + jB];
                Tm[t] = a;
            }
            __syncthreads();
            int nB = sA * sA;
            if (t < nB) {
                int iA = t / sA, jA = t - iA * sA;
                float a = 0.f;
                for (int iB = 0; iB < sB; ++iB)
                    a += Gp[iA * sB + iB] * Tm[iB * sA + jA];
                pv += factor * ybuf[yAoff + t] * a;
            }
        }

#pragma unroll
        for (int off = 1; off < 64; off <<= 1) {
            pu += __shfl_xor(pu, off);
            pv += __shfl_xor(pv, off);
        }
        __syncthreads();
        if ((t & 63) == 0) { red[(t >> 6) * 2] = pu; red[(t >> 6) * 2 + 1] = pv; }
        __syncthreads();
        if (t == 0) {
            float puT = red[0] + red[2] + red[4] + red[6];
            float pvT = red[1] + red[3] + red[5] + red[7];
            float fb = fusion_b[c];
            float s1 = sx[(b * 256 + c) * 2], s2 = sx[(b * 256 + c) * 2 + 1];
            double S1 = (double)s1 + 65536.0 * (double)fb + (double)puT;
            double S2 = (double)s2 + 2.0 * (double)fb * (double)s1 +
                        65536.0 * (double)fb * (double)fb +
                        2.0 * (double)fb * (double)puT + (double)pvT;
            gS1 += S1; gS2 += S2;
        }
        __syncthreads();
    }

    if (t == 0) {
        double mean = gS1 / 524288.0;
        double var  = gS2 / 524288.0 - mean * mean;
        stats_g[bg * 2] = (float)mean;
        stats_g[bg * 2 + 1] = (float)(1.0 / sqrt(var + 1e-5));
    }
}

// ---------------------------------------------------------------------------
// K5: final pass — recompute f via LDS-blended interp, normalize, write.
// (unchanged, validated)
// ---------------------------------------------------------------------------
__global__ __launch_bounds__(256) void write_kernel(
    const float* __restrict__ x,
    const float* __restrict__ ws_y4, const float* __restrict__ ws_y8,
    const float* __restrict__ ws_y16,
    const float* __restrict__ fusion_b,
    const float* __restrict__ gn_w, const float* __restrict__ gn_b,
    const float* __restrict__ stats_g,
    float* __restrict__ out) {

    __shared__ float ly16[256], ly8[64], ly4[16];
    __shared__ float2 rbd16[16][16];
    __shared__ float2 rbd8[16][8];
    __shared__ float2 rbd4[16][4];

    int blk = blockIdx.x;
    int hblk = blk & 15;
    int c = (blk >> 4) & 255;
    int b = blk >> 12;
    int t = threadIdx.x;

    ly16[t] = ws_y16[(size_t)(b * 256 + c) * 256 + t];
    if (t < 64) ly8[t] = ws_y8[(size_t)(b * 256 + c) * 64 + t];
    if (t < 16) ly4[t] = ws_y4[(size_t)(b * 256 + c) * 16 + t];
    __syncthreads();

    for (int idx = t; idx < 448; idx += 256) {
        int r = idx / 28;
        int q = idx - r * 28;
        int h = hblk * 16 + r;
        if (q < 16) {
            float src = (h + 0.5f) * 0.0625f - 0.5f;
            src = fminf(fmaxf(src, 0.f), 15.f);
            int lo = (int)src; float wf = src - lo; int hi = min(lo + 1, 15);
            float rb = (1.f - wf) * ly16[lo * 16 + q] + wf * ly16[hi * 16 + q];
            rbd16[r][q].x = rb;
            if (q > 0) rbd16[r][q - 1].y = rb;
            if (q == 15) rbd16[r][15].y = rb;
        } else if (q < 24) {
            int jj = q - 16;
            float src = (h + 0.5f) * 0.03125f - 0.5f;
            src = fminf(fmaxf(src, 0.f), 7.f);
            int lo = (int)src; float wf = src - lo; int hi = min(lo + 1, 7);
            float rb = (1.f - wf) * ly8[lo * 8 + jj] + wf * ly8[hi * 8 + jj];
            rbd8[r][jj].x = rb;
            if (jj > 0) rbd8[r][jj - 1].y = rb;
            if (jj == 7) rbd8[r][7].y = rb;
        } else {
            int jj = q - 24;
            float src = (h + 0.5f) * 0.015625f - 0.5f;
            src = fminf(fmaxf(src, 0.f), 3.f);
            int lo = (int)src; float wf = src - lo; int hi = min(lo + 1, 3);
            float rb = (1.f - wf) * ly4[lo * 4 + jj] + wf * ly4[hi * 4 + jj];
            rbd4[r][jj].x = rb;
            if (jj > 0) rbd4[r][jj - 1].y = rb;
            if (jj == 3) rbd4[r][3].y = rb;
        }
    }
    __syncthreads();

    int w4 = t & 63;
    int wg = t >> 6;
    int w0 = w4 * 4;

    int jlo16[4], jlo8[4], jlo4[4];
    float ww16[4], ww8[4], ww4[4];
#pragma unroll
    for (int p = 0; p < 4; ++p) {
        int w = w0 + p;
        float s16 = fminf(fmaxf((w + 0.5f) * 0.0625f - 0.5f, 0.f), 15.f);
        jlo16[p] = (int)s16; ww16[p] = s16 - jlo16[p];
        float s8 = fminf(fmaxf((w + 0.5f) * 0.03125f - 0.5f, 0.f), 7.f);
        jlo8[p] = (int)s8; ww8[p] = s8 - jlo8[p];
        float s4 = fminf(fmaxf((w + 0.5f) * 0.015625f - 0.5f, 0.f), 3.f);
        jlo4[p] = (int)s4; ww4[p] = s4 - jlo4[p];
    }

    float fb_c = fusion_b[c];
    int gidx = c >> 3;
    float mean = stats_g[(b * 32 + gidx) * 2];
    float rstd = stats_g[(b * 32 + gidx) * 2 + 1];
    float gwc = gn_w[c], gbc = gn_b[c];

    const float4* xp = (const float4*)(x + (size_t)(b * 256 + c) * (H * Wd));
    float4* op = (float4*)(out + (size_t)(b * 256 + c) * (H * Wd));

#pragma unroll
    for (int it = 0; it < 4; ++it) {
        int r = it * 4 + wg;
        int idx4 = (hblk * 16 + r) * 64 + w4;
        float4 xv = xp[idx4];
        float res[4];
        float px[4] = {xv.x, xv.y, xv.z, xv.w};
#pragma unroll
        for (int p = 0; p < 4; ++p) {
            float f = fb_c;
            float2 v16 = rbd16[r][jlo16[p]];
            f += (1.f - ww16[p]) * v16.x + ww16[p] * v16.y;
            float2 v8 = rbd8[r][jlo8[p]];
            f += (1.f - ww8[p]) * v8.x + ww8[p] * v8.y;
            float2 v4 = rbd4[r][jlo4[p]];
            f += (1.f - ww4[p]) * v4.x + ww4[p] * v4.y;
            float tv = px[p] + f;
            res[p] = (tv - mean) * rstd * gwc + gbc;
        }
        op[idx4] = make_float4(res[0], res[1], res[2], res[3]);
    }
}

// ---------------------------------------------------------------------------
extern "C" void kernel_launch(void* const* d_in, const int* in_sizes, int n_in,
                              void* d_out, int out_size, void* d_ws, size_t ws_size,
                              hipStream_t stream) {
    const float* x   = (const float*)d_in[0];
    const float* cw0 = (const float*)d_in[1];
    const float* cw1 = (const float*)d_in[2];
    const float* cw2 = (const float*)d_in[3];
    const float* sw0 = (const float*)d_in[4];
    const float* sw1 = (const float*)d_in[5];
    const float* sw2 = (const float*)d_in[6];
    const float* fw  = (const float*)d_in[7];
    const float* fb  = (const float*)d_in[8];
    const float* gw  = (const float*)d_in[9];
    const float* gb  = (const float*)d_in[10];
    float* out = (float*)d_out;

    float* ws     = (float*)d_ws;
    float* pool16 = ws;                    // 262144
    float* y4     = pool16 + 262144;       // 16384
    float* y8     = y4 + 16384;            // 65536
    float* y16    = y8 + 65536;            // 262144
    float* xp16   = y16 + 262144;          // 262144
    float* xp8    = xp16 + 262144;         // 65536
    float* xp4    = xp8 + 65536;           // 16384
    float* sx     = xp4 + 16384;           // 2048
    float* statsg = sx + 2048;             // 256
    float* Rbuf   = statsg + 256;          // 1024*7168 = 7340032
    float* sxpart = Rbuf + 7340032;        // 32768

    xread_kernel<<<B * C * 16, 256, 0, stream>>>(x, pool16, Rbuf, sxpart);
    proj_kernel<<<B * C, 256, 0, stream>>>(Rbuf, sxpart, xp16, xp8, xp4, sx);
    site_kernel<<<B * 336, 256, 0, stream>>>(pool16, cw0, cw1, cw2,
                                             sw0, sw1, sw2, fw, y4, y8, y16);
    groupstats_kernel<<<B * 32, 256, 0, stream>>>(y4, y8, y16, xp4, xp8, xp16,
                                                  sx, fb, statsg);
    write_kernel<<<B * C * 16, 256, 0, stream>>>(x, y4, y8, y16, fb, gw, gb,
                                                 statsg, out);
}

// Round 6
// 284.597 us; speedup vs baseline: 1.3976x; 1.1171x over previous
//
#include <hip/hip_runtime.h>
#include <hip/hip_bf16.h>
#include <math.h>

#define B 4
#define C 256
#define H 256
#define Wd 256

// ---------------------------------------------------------------------------
// K1 (stage A): streaming x pass. Block = (plane, 16-row slab). 16384 blocks.
// Per row, lane l (pixels 4l..4l+3) computes per scale (u = p0-S, S) with
// S = alpha*p0 + beta*pw (validated). Values land in GUARDED LDS arrays so
// the column-reduce is static-count (fully unrolled, independent reads):
//   col j (s16): 4 reads BU16[4j+2..] + 4 reads BS16[4j..] (+u[0..1] if j==0)
//   col j (s8) : 8 + 8  (+u[0..3] if j==0)
//   col j (s4) : 16 + 16 (+u[0..7] if j==0)
// Guards make edge columns identical to the validated runtime-bound sums.
// ---------------------------------------------------------------------------
__global__ __launch_bounds__(256) void xread_kernel(
    const float* __restrict__ x,
    float* __restrict__ pool16,     // [1024][256]
    float* __restrict__ Rbuf,       // [1024][256][28]
    float* __restrict__ sxpart) {   // [16384][2]

    __shared__ float BU16[16][66], BS16[16][66];
    __shared__ float BU8[16][68],  BS8[16][68];
    __shared__ float BU4[16][72],  BS4[16][72];
    __shared__ float P0[16][64];
    __shared__ float rs[4][2];

    int blk = blockIdx.x;
    int slab = blk & 15;
    int bc = blk >> 4;
    int t = threadIdx.x;
    int wg = t >> 6, l = t & 63;

    // guard zeros: 28 per row
    for (int e = t; e < 448; e += 256) {
        int r = e / 28, g = e - r * 28;
        if (g < 2)       BU16[r][64 + g] = 0.f;
        else if (g < 4)  BS16[r][g - 2] = 0.f;
        else if (g < 8)  BU8[r][64 + (g - 4)] = 0.f;
        else if (g < 12) BS8[r][g - 8] = 0.f;
        else if (g < 20) BU4[r][64 + (g - 12)] = 0.f;
        else             BS4[r][g - 20] = 0.f;
    }

    const float4* xp = (const float4*)(x + (size_t)bc * (H * Wd));

    // per-lane w-side constants (validated)
    float a16, b16, a8, b8, a4, b4;
    {
        float w0 = 4.f * (float)l + 0.5f;
        float s16v = w0 * 0.0625f - 0.5f;
        if (l <= 1 || l >= 62) { a16 = 0.f; b16 = 0.f; }
        else { a16 = s16v - floorf(s16v); b16 = 0.0625f; }
        float s8v = w0 * 0.03125f - 0.5f;
        if (l <= 3 || l >= 60) { a8 = 0.f; b8 = 0.f; }
        else { a8 = s8v - floorf(s8v); b8 = 0.03125f; }
        float s4v = w0 * 0.015625f - 0.5f;
        if (l <= 7 || l >= 56) { a4 = 0.f; b4 = 0.f; }
        else { a4 = s4v - floorf(s4v); b4 = 0.015625f; }
    }

    float sx1 = 0.f, sx2 = 0.f;
    float4 v[4];
#pragma unroll
    for (int it = 0; it < 4; ++it)
        v[it] = xp[(slab * 16 + wg * 4 + it) * 64 + l];

#pragma unroll
    for (int it = 0; it < 4; ++it) {
        int r = wg * 4 + it;
        float4 vv = v[it];
        float p0 = (vv.x + vv.y) + (vv.z + vv.w);
        float pw = fmaf(3.f, vv.w, fmaf(2.f, vv.z, vv.y));
        sx1 += p0;
        sx2 += vv.x * vv.x + vv.y * vv.y + vv.z * vv.z + vv.w * vv.w;
        float S16 = fmaf(b16, pw, a16 * p0);
        float S8  = fmaf(b8,  pw, a8  * p0);
        float S4  = fmaf(b4,  pw, a4  * p0);
        BU16[r][l] = p0 - S16;  BS16[r][2 + l] = S16;
        BU8[r][l]  = p0 - S8;   BS8[r][4 + l]  = S8;
        BU4[r][l]  = p0 - S4;   BS4[r][8 + l]  = S4;
        P0[r][l] = p0;
    }

    // per-wave sx reduce (validated pattern)
#pragma unroll
    for (int off = 1; off < 64; off <<= 1) {
        sx1 += __shfl_xor(sx1, off);
        sx2 += __shfl_xor(sx2, off);
    }
    if (l == 0) { rs[wg][0] = sx1; rs[wg][1] = sx2; }
    __syncthreads();

    // static-count column-reduce tasks: 448 rowproj + 16 pool
    size_t rowbase = ((size_t)bc * 256 + slab * 16);
    for (int tk = t; tk < 464; tk += 256) {
        if (tk < 256) {                       // s16: r=tk>>4, j=tk&15
            int r = tk >> 4, j = tk & 15;
            float sum = 0.f;
#pragma unroll
            for (int k = 0; k < 4; ++k) sum += BU16[r][4 * j + 2 + k];
#pragma unroll
            for (int k = 0; k < 4; ++k) sum += BS16[r][4 * j + k];
            if (j == 0) sum += BU16[r][0] + BU16[r][1];
            Rbuf[(rowbase + r) * 28 + j] = sum;
        } else if (tk < 384) {                // s8
            int q = tk - 256; int r = q >> 3, j = q & 7;
            float sum = 0.f;
#pragma unroll
            for (int k = 0; k < 8; ++k) sum += BU8[r][8 * j + 4 + k];
#pragma unroll
            for (int k = 0; k < 8; ++k) sum += BS8[r][8 * j + k];
            if (j == 0) sum += BU8[r][0] + BU8[r][1] + BU8[r][2] + BU8[r][3];
            Rbuf[(rowbase + r) * 28 + 16 + j] = sum;
        } else if (tk < 448) {                // s4
            int q = tk - 384; int r = q >> 2, j = q & 3;
            float sum = 0.f;
#pragma unroll
            for (int k = 0; k < 16; ++k) sum += BU4[r][16 * j + 8 + k];
#pragma unroll
            for (int k = 0; k < 16; ++k) sum += BS4[r][16 * j + k];
            if (j == 0) {
#pragma unroll
                for (int k = 0; k < 8; ++k) sum += BU4[r][k];
            }
            Rbuf[(rowbase + r) * 28 + 24 + j] = sum;
        } else {                              // pool: j = tk-448
            int j = tk - 448;
            float sum = 0.f;
#pragma unroll
            for (int r2 = 0; r2 < 16; ++r2) {
#pragma unroll
                for (int k = 0; k < 4; ++k) sum += P0[r2][4 * j + k];
            }
            pool16[(size_t)bc * 256 + slab * 16 + j] = sum * (1.f / 256.f);
        }
    }
    if (t == 0) {
        sxpart[(size_t)blk * 2]     = rs[0][0] + rs[1][0] + rs[2][0] + rs[3][0];
        sxpart[(size_t)blk * 2 + 1] = rs[0][1] + rs[1][1] + rs[2][1] + rs[3][1];
    }
}

// ---------------------------------------------------------------------------
// K2 (stage B): fold R rowproj with h-interp weights -> xproj16/8/4; fold
// sx partials. One block per plane (1024 blocks). (unchanged, validated)
// ---------------------------------------------------------------------------
__global__ __launch_bounds__(256) void proj_kernel(
    const float* __restrict__ Rbuf, const float* __restrict__ sxpart,
    float* __restrict__ xp16o, float* __restrict__ xp8o,
    float* __restrict__ xp4o, float* __restrict__ sx) {

    __shared__ float Rl[256 * 29];   // padded stride 29

    int bc = blockIdx.x;
    int t = threadIdx.x;

    const float* rp = Rbuf + (size_t)bc * 7168;
    for (int e = t; e < 7168; e += 256) {
        int r = e / 28, c = e - r * 28;
        Rl[r * 29 + c] = rp[e];
    }
    __syncthreads();

    {
        int i = t >> 4, j = t & 15;
        float acc = 0.f;
        int r0 = max(0, 16 * i - 8), r1 = min(255, 16 * i + 23);
        for (int r = r0; r <= r1; ++r) {
            float src = fminf(fmaxf(((float)r + 0.5f) * 0.0625f - 0.5f, 0.f), 15.f);
            int lo = (int)src; float fr = src - (float)lo;
            float w = (i == lo) ? (1.f - fr) : ((i == lo + 1) ? fr : 0.f);
            acc += w * Rl[r * 29 + j];
        }
        xp16o[(size_t)bc * 256 + t] = acc;
    }
    if (t < 64) {
        int i = t >> 3, j = t & 7;
        float acc = 0.f;
        int r0 = max(0, 32 * i - 16), r1 = min(255, 32 * i + 47);
        for (int r = r0; r <= r1; ++r) {
            float src = fminf(fmaxf(((float)r + 0.5f) * 0.03125f - 0.5f, 0.f), 7.f);
            int lo = (int)src; float fr = src - (float)lo;
            float w = (i == lo) ? (1.f - fr) : ((i == lo + 1) ? fr : 0.f);
            acc += w * Rl[r * 29 + 16 + j];
        }
        xp8o[(size_t)bc * 64 + t] = acc;
    } else if (t < 80) {
        int e = t - 64;
        int i = e >> 2, j = e & 3;
        float acc = 0.f;
        int r0 = max(0, 64 * i - 32), r1 = min(255, 64 * i + 95);
        for (int r = r0; r <= r1; ++r) {
            float src = fminf(fmaxf(((float)r + 0.5f) * 0.015625f - 0.5f, 0.f), 3.f);
            int lo = (int)src; float fr = src - (float)lo;
            float w = (i == lo) ? (1.f - fr) : ((i == lo + 1) ? fr : 0.f);
            acc += w * Rl[r * 29 + 24 + j];
        }
        xp4o[(size_t)bc * 16 + e] = acc;
    } else if (t == 128) {
        float s1 = 0.f, s2 = 0.f;
        for (int k = 0; k < 16; ++k) {
            s1 += sxpart[(size_t)(bc * 16 + k) * 2];
            s2 += sxpart[(size_t)(bc * 16 + k) * 2 + 1];
        }
        sx[bc * 2] = s1; sx[bc * 2 + 1] = s2;
    }
}

// ---------------------------------------------------------------------------
// K3: per (b, scale, site) attention + channel-mix. (unchanged, validated)
// ---------------------------------------------------------------------------
__global__ __launch_bounds__(256) void site_kernel(
    const float* __restrict__ pool16,
    const float* __restrict__ cw0, const float* __restrict__ cw1,
    const float* __restrict__ cw2,
    const float* __restrict__ sw0, const float* __restrict__ sw1,
    const float* __restrict__ sw2,
    const float* __restrict__ fusion_w,
    float* __restrict__ y4, float* __restrict__ y8, float* __restrict__ y16) {

    __shared__ float P[256];
    __shared__ float Wm[961];
    __shared__ float QKV[279];
    __shared__ float QW[93];
    __shared__ float A[9];
    __shared__ float OUTV[93];

    int t = threadIdx.x;
    int blk = blockIdx.x;
    int b = blk / 336;
    int r = blk % 336;

    int s, site, foff;
    const float* cw; const float* sw; float* yout;
    if (r < 256)      { s = 16; site = r;       cw = cw2; sw = sw2; foff = 186; yout = y16; }
    else if (r < 320) { s = 8;  site = r - 256; cw = cw1; sw = sw1; foff = 93;  yout = y8;  }
    else              { s = 4;  site = r - 320; cw = cw0; sw = sw0; foff = 0;   yout = y4;  }
    int i = site / s, j = site % s;

    for (int idx = t; idx < 961; idx += 256) Wm[idx] = sw[idx];

    {
        int f = 16 / s;
        float acc = 0.f;
        int base = (b * 256 + t) * 256;
        for (int ii = 0; ii < f; ++ii)
            for (int jj = 0; jj < f; ++jj)
                acc += pool16[base + (i * f + ii) * 16 + (j * f + jj)];
        P[t] = acc / (float)(f * f);
    }
    __syncthreads();

    for (int o = t; o < 279; o += 256) {
        const float4* wrow = (const float4*)(cw + o * 256);
        float acc = 0.f;
#pragma unroll 8
        for (int c4 = 0; c4 < 64; ++c4) {
            float4 wv = wrow[c4];
            acc += wv.x * P[c4 * 4] + wv.y * P[c4 * 4 + 1] +
                   wv.z * P[c4 * 4 + 2] + wv.w * P[c4 * 4 + 3];
        }
        QKV[o] = acc;
    }
    __syncthreads();

    if (t < 93) {
        int g = t / 31, m = t % 31;
        float acc = 0.f;
        for (int n = 0; n < 31; ++n) acc += QKV[g * 31 + n] * Wm[n * 31 + m];
        QW[t] = acc;
    }
    __syncthreads();
    if (t < 9) {
        int g = t / 3, h = t % 3;
        float acc = 0.f;
        for (int m = 0; m < 31; ++m) acc += QW[g * 31 + m] * QKV[93 + h * 31 + m];
        A[t] = acc * 0.57735026918962576f;
    }
    __syncthreads();
    if (t < 3) {
        float a0 = A[t * 3], a1 = A[t * 3 + 1], a2 = A[t * 3 + 2];
        float mx = fmaxf(a0, fmaxf(a1, a2));
        float e0 = expf(a0 - mx), e1 = expf(a1 - mx), e2 = expf(a2 - mx);
        float inv = 1.0f / (e0 + e1 + e2);
        A[t * 3] = e0 * inv; A[t * 3 + 1] = e1 * inv; A[t * 3 + 2] = e2 * inv;
    }
    __syncthreads();
    if (t < 93) {
        int g = t / 31, n = t % 31;
        OUTV[t] = A[g * 3] * QKV[186 + n] + A[g * 3 + 1] * QKV[186 + 31 + n] +
                  A[g * 3 + 2] * QKV[186 + 62 + n];
    }
    __syncthreads();
    {
        const float* fr = fusion_w + t * 279 + foff;
        float acc = 0.f;
#pragma unroll 31
        for (int c = 0; c < 93; ++c) acc += fr[c] * OUTV[c];
        yout[(size_t)(b * 256 + t) * (s * s) + site] = acc;
    }
}

// ---------------------------------------------------------------------------
// K4: GroupNorm stats WITHOUT touching x. (unchanged, validated)
// ---------------------------------------------------------------------------
__global__ __launch_bounds__(256) void groupstats_kernel(
    const float* __restrict__ y4, const float* __restrict__ y8,
    const float* __restrict__ y16,
    const float* __restrict__ xp4, const float* __restrict__ xp8,
    const float* __restrict__ xp16,
    const float* __restrict__ sx, const float* __restrict__ fusion_b,
    float* __restrict__ stats_g) {

    __shared__ float G1616[256], G168[128], G164[64], G88[64], G84[32], G44[16];
    __shared__ float cs[28];
    __shared__ float ybuf[336], xbuf[336];
    __shared__ float Tm[256];
    __shared__ float red[8];

    int t = threadIdx.x;
    int bg = blockIdx.x;
    int b = bg >> 5, g = bg & 31;

    for (int e = t; e < 588; e += 256) {
        if (e >= 560) {
            int q = e - 560; int sC, iC;
            if (q < 16) { sC = 16; iC = q; }
            else if (q < 24) { sC = 8; iC = q - 16; }
            else { sC = 4; iC = q - 24; }
            int R = 256 / sC;
            int lo = max(0, R * iC - R / 2), hi = min(256, R * iC + (3 * R) / 2);
            float Rinv = 1.f / (float)R, smax = (float)(sC - 1);
            float a = 0.f;
            for (int h = lo; h < hi; ++h) {
                float src = fminf(fmaxf(((float)h + 0.5f) * Rinv - 0.5f, 0.f), smax);
                int lq = (int)src; float fr = src - (float)lq;
                a += (iC == lq) ? (1.f - fr) : ((iC == lq + 1) ? fr : 0.f);
            }
            cs[q] = a;
            continue;
        }
        int sA, sB, iA, iB; float* dst; int off;
        if (e < 256)      { sA = 16; sB = 16; iA = e >> 4; iB = e & 15; dst = G1616; off = e; }
        else if (e < 384) { int q = e - 256; sA = 16; sB = 8; iA = q >> 3; iB = q & 7; dst = G168; off = q; }
        else if (e < 448) { int q = e - 384; sA = 16; sB = 4; iA = q >> 2; iB = q & 3; dst = G164; off = q; }
        else if (e < 512) { int q = e - 448; sA = 8;  sB = 8; iA = q >> 3; iB = q & 7; dst = G88;  off = q; }
        else if (e < 544) { int q = e - 512; sA = 8;  sB = 4; iA = q >> 2; iB = q & 3; dst = G84;  off = q; }
        else              { int q = e - 544; sA = 4;  sB = 4; iA = q >> 2; iB = q & 3; dst = G44;  off = q; }
        int RA = 256 / sA, RB = 256 / sB;
        int lo = max(max(0, RA * iA - RA / 2), RB * iB - RB / 2);
        int hi = min(min(256, RA * iA + (3 * RA) / 2), RB * iB + (3 * RB) / 2);
        float RAi = 1.f / (float)RA, RBi = 1.f / (float)RB;
        float smA = (float)(sA - 1), smB = (float)(sB - 1);
        float a = 0.f;
        for (int h = lo; h < hi; ++h) {
            float sa = fminf(fmaxf(((float)h + 0.5f) * RAi - 0.5f, 0.f), smA);
            int la = (int)sa; float fa = sa - (float)la;
            float wa = (iA == la) ? (1.f - fa) : ((iA == la + 1) ? fa : 0.f);
            float sb = fminf(fmaxf(((float)h + 0.5f) * RBi - 0.5f, 0.f), smB);
            int lb = (int)sb; float fb_ = sb - (float)lb;
            float wb = (iB == lb) ? (1.f - fb_) : ((iB == lb + 1) ? fb_ : 0.f);
            a += wa * wb;
        }
        dst[off] = a;
    }
    __syncthreads();

    double gS1 = 0.0, gS2 = 0.0;

    for (int c8 = 0; c8 < 8; ++c8) {
        int c = g * 8 + c8;
        size_t bc = (size_t)(b * 256 + c);
        ybuf[t] = y16[bc * 256 + t];
        xbuf[t] = xp16[bc * 256 + t];
        if (t < 64) { ybuf[256 + t] = y8[bc * 64 + t]; xbuf[256 + t] = xp8[bc * 64 + t]; }
        else if (t < 80) { ybuf[256 + t] = y4[bc * 16 + (t - 64)]; xbuf[256 + t] = xp4[bc * 16 + (t - 64)]; }
        __syncthreads();

        float pu = 0.f, pv = 0.f;
        for (int e = t; e < 336; e += 256) {
            float yv = ybuf[e];
            pv += 2.f * yv * xbuf[e];
            int ci, cj;
            if (e < 256)      { ci = e >> 4;               cj = e & 15; }
            else if (e < 320) { ci = 16 + ((e - 256) >> 3); cj = 16 + ((e - 256) & 7); }
            else              { ci = 24 + ((e - 320) >> 2); cj = 24 + ((e - 320) & 3); }
            pu += yv * cs[ci] * cs[cj];
        }

        for (int p = 0; p < 6; ++p) {
            const float* Gp; int sA, sB, yAoff, yBoff; float factor;
            switch (p) {
                case 0: Gp = G1616; sA = 16; sB = 16; yAoff = 0;   yBoff = 0;   factor = 1.f; break;
                case 1: Gp = G168;  sA = 16; sB = 8;  yAoff = 0;   yBoff = 256; factor = 2.f; break;
                case 2: Gp = G164;  sA = 16; sB = 4;  yAoff = 0;   yBoff = 320; factor = 2.f; break;
                case 3: Gp = G88;   sA = 8;  sB = 8;  yAoff = 256; yBoff = 256; factor = 1.f; break;
                case 4: Gp = G84;   sA = 8;  sB = 4;  yAoff = 256; yBoff = 320; factor = 2.f; break;
                default:Gp = G44;   sA = 4;  sB = 4;  yAoff = 320; yBoff = 320; factor = 1.f; break;
            }
            __syncthreads();
            int nT = sB * sA;
            if (t < nT) {
                int iB = t / sA, jA = t - iB * sA;
                float a = 0.f;
                for (int jB = 0; jB < sB; ++jB)
                    a += Gp[jA * sB + jB] * ybuf[yBoff + iB * sB + jB];
                Tm[t] = a;
            }
            __syncthreads();
            int nB = sA * sA;
            if (t < nB) {
                int iA = t / sA, jA = t - iA * sA;
                float a = 0.f;
                for (int iB = 0; iB < sB; ++iB)
                    a += Gp[iA * sB + iB] * Tm[iB * sA + jA];
                pv += factor * ybuf[yAoff + t] * a;
            }
        }

#pragma unroll
        for (int off = 1; off < 64; off <<= 1) {
            pu += __shfl_xor(pu, off);
            pv += __shfl_xor(pv, off);
        }
        __syncthreads();
        if ((t & 63) == 0) { red[(t >> 6) * 2] = pu; red[(t >> 6) * 2 + 1] = pv; }
        __syncthreads();
        if (t == 0) {
            float puT = red[0] + red[2] + red[4] + red[6];
            float pvT = red[1] + red[3] + red[5] + red[7];
            float fb = fusion_b[c];
            float s1 = sx[(b * 256 + c) * 2], s2 = sx[(b * 256 + c) * 2 + 1];
            double S1 = (double)s1 + 65536.0 * (double)fb + (double)puT;
            double S2 = (double)s2 + 2.0 * (double)fb * (double)s1 +
                        65536.0 * (double)fb * (double)fb +
                        2.0 * (double)fb * (double)puT + (double)pvT;
            gS1 += S1; gS2 += S2;
        }
        __syncthreads();
    }

    if (t == 0) {
        double mean = gS1 / 524288.0;
        double var  = gS2 / 524288.0 - mean * mean;
        stats_g[bg * 2] = (float)mean;
        stats_g[bg * 2 + 1] = (float)(1.0 / sqrt(var + 1e-5));
    }
}

// ---------------------------------------------------------------------------
// K5: final pass — recompute f via LDS-blended interp, normalize, write.
// (unchanged, validated)
// ---------------------------------------------------------------------------
__global__ __launch_bounds__(256) void write_kernel(
    const float* __restrict__ x,
    const float* __restrict__ ws_y4, const float* __restrict__ ws_y8,
    const float* __restrict__ ws_y16,
    const float* __restrict__ fusion_b,
    const float* __restrict__ gn_w, const float* __restrict__ gn_b,
    const float* __restrict__ stats_g,
    float* __restrict__ out) {

    __shared__ float ly16[256], ly8[64], ly4[16];
    __shared__ float2 rbd16[16][16];
    __shared__ float2 rbd8[16][8];
    __shared__ float2 rbd4[16][4];

    int blk = blockIdx.x;
    int hblk = blk & 15;
    int c = (blk >> 4) & 255;
    int b = blk >> 12;
    int t = threadIdx.x;

    ly16[t] = ws_y16[(size_t)(b * 256 + c) * 256 + t];
    if (t < 64) ly8[t] = ws_y8[(size_t)(b * 256 + c) * 64 + t];
    if (t < 16) ly4[t] = ws_y4[(size_t)(b * 256 + c) * 16 + t];
    __syncthreads();

    for (int idx = t; idx < 448; idx += 256) {
        int r = idx / 28;
        int q = idx - r * 28;
        int h = hblk * 16 + r;
        if (q < 16) {
            float src = (h + 0.5f) * 0.0625f - 0.5f;
            src = fminf(fmaxf(src, 0.f), 15.f);
            int lo = (int)src; float wf = src - lo; int hi = min(lo + 1, 15);
            float rb = (1.f - wf) * ly16[lo * 16 + q] + wf * ly16[hi * 16 + q];
            rbd16[r][q].x = rb;
            if (q > 0) rbd16[r][q - 1].y = rb;
            if (q == 15) rbd16[r][15].y = rb;
        } else if (q < 24) {
            int jj = q - 16;
            float src = (h + 0.5f) * 0.03125f - 0.5f;
            src = fminf(fmaxf(src, 0.f), 7.f);
            int lo = (int)src; float wf = src - lo; int hi = min(lo + 1, 7);
            float rb = (1.f - wf) * ly8[lo * 8 + jj] + wf * ly8[hi * 8 + jj];
            rbd8[r][jj].x = rb;
            if (jj > 0) rbd8[r][jj - 1].y = rb;
            if (jj == 7) rbd8[r][7].y = rb;
        } else {
            int jj = q - 24;
            float src = (h + 0.5f) * 0.015625f - 0.5f;
            src = fminf(fmaxf(src, 0.f), 3.f);
            int lo = (int)src; float wf = src - lo; int hi = min(lo + 1, 3);
            float rb = (1.f - wf) * ly4[lo * 4 + jj] + wf * ly4[hi * 4 + jj];
            rbd4[r][jj].x = rb;
            if (jj > 0) rbd4[r][jj - 1].y = rb;
            if (jj == 3) rbd4[r][3].y = rb;
        }
    }
    __syncthreads();

    int w4 = t & 63;
    int wg = t >> 6;
    int w0 = w4 * 4;

    int jlo16[4], jlo8[4], jlo4[4];
    float ww16[4], ww8[4], ww4[4];
#pragma unroll
    for (int p = 0; p < 4; ++p) {
        int w = w0 + p;
        float s16 = fminf(fmaxf((w + 0.5f) * 0.0625f - 0.5f, 0.f), 15.f);
        jlo16[p] = (int)s16; ww16[p] = s16 - jlo16[p];
        float s8 = fminf(fmaxf((w + 0.5f) * 0.03125f - 0.5f, 0.f), 7.f);
        jlo8[p] = (int)s8; ww8[p] = s8 - jlo8[p];
        float s4 = fminf(fmaxf((w + 0.5f) * 0.015625f - 0.5f, 0.f), 3.f);
        jlo4[p] = (int)s4; ww4[p] = s4 - jlo4[p];
    }

    float fb_c = fusion_b[c];
    int gidx = c >> 3;
    float mean = stats_g[(b * 32 + gidx) * 2];
    float rstd = stats_g[(b * 32 + gidx) * 2 + 1];
    float gwc = gn_w[c], gbc = gn_b[c];

    const float4* xp = (const float4*)(x + (size_t)(b * 256 + c) * (H * Wd));
    float4* op = (float4*)(out + (size_t)(b * 256 + c) * (H * Wd));

#pragma unroll
    for (int it = 0; it < 4; ++it) {
        int r = it * 4 + wg;
        int idx4 = (hblk * 16 + r) * 64 + w4;
        float4 xv = xp[idx4];
        float res[4];
        float px[4] = {xv.x, xv.y, xv.z, xv.w};
#pragma unroll
        for (int p = 0; p < 4; ++p) {
            float f = fb_c;
            float2 v16 = rbd16[r][jlo16[p]];
            f += (1.f - ww16[p]) * v16.x + ww16[p] * v16.y;
            float2 v8 = rbd8[r][jlo8[p]];
            f += (1.f - ww8[p]) * v8.x + ww8[p] * v8.y;
            float2 v4 = rbd4[r][jlo4[p]];
            f += (1.f - ww4[p]) * v4.x + ww4[p] * v4.y;
            float tv = px[p] + f;
            res[p] = (tv - mean) * rstd * gwc + gbc;
        }
        op[idx4] = make_float4(res[0], res[1], res[2], res[3]);
    }
}

// ---------------------------------------------------------------------------
extern "C" void kernel_launch(void* const* d_in, const int* in_sizes, int n_in,
                              void* d_out, int out_size, void* d_ws, size_t ws_size,
                              hipStream_t stream) {
    const float* x   = (const float*)d_in[0];
    const float* cw0 = (const float*)d_in[1];
    const float* cw1 = (const float*)d_in[2];
    const float* cw2 = (const float*)d_in[3];
    const float* sw0 = (const float*)d_in[4];
    const float* sw1 = (const float*)d_in[5];
    const float* sw2 = (const float*)d_in[6];
    const float* fw  = (const float*)d_in[7];
    const float* fb  = (const float*)d_in[8];
    const float* gw  = (const float*)d_in[9];
    const float* gb  = (const float*)d_in[10];
    float* out = (float*)d_out;

    float* ws     = (float*)d_ws;
    float* pool16 = ws;                    // 262144
    float* y4     = pool16 + 262144;       // 16384
    float* y8     = y4 + 16384;            // 65536
    float* y16    = y8 + 65536;            // 262144
    float* xp16   = y16 + 262144;          // 262144
    float* xp8    = xp16 + 262144;         // 65536
    float* xp4    = xp8 + 65536;           // 16384
    float* sx     = xp4 + 16384;           // 2048
    float* statsg = sx + 2048;             // 256
    float* Rbuf   = statsg + 256;          // 1024*7168 = 7340032
    float* sxpart = Rbuf + 7340032;        // 32768

    xread_kernel<<<B * C * 16, 256, 0, stream>>>(x, pool16, Rbuf, sxpart);
    proj_kernel<<<B * C, 256, 0, stream>>>(Rbuf, sxpart, xp16, xp8, xp4, sx);
    site_kernel<<<B * 336, 256, 0, stream>>>(pool16, cw0, cw1, cw2,
                                             sw0, sw1, sw2, fw, y4, y8, y16);
    groupstats_kernel<<<B * 32, 256, 0, stream>>>(y4, y8, y16, xp4, xp8, xp16,
                                                  sx, fb, statsg);
    write_kernel<<<B * C * 16, 256, 0, stream>>>(x, y4, y8, y16, fb, gw, gb,
                                                 statsg, out);
}

// Round 7
// 278.063 us; speedup vs baseline: 1.4304x; 1.0235x over previous
//
#include <hip/hip_runtime.h>
#include <hip/hip_bf16.h>
#include <math.h>

#define B 4
#define C 256
#define H 256
#define Wd 256

// ---------------------------------------------------------------------------
// K1: plane-per-block streaming pass over x (1024 blocks). 16 slabs of 16
// rows, software-pipelined 1-deep: slab k+1 loads (to REGISTERS - no vmcnt
// drain at barriers) issue before slab k's merge. R stays in LDS (no Rbuf).
// Per slab: guarded-LDS static-count column reduce (validated round 6).
// Tail: h-fold (validated proj_kernel loops) -> xp16/8/4; reg-accumulated
// sx -> wave reduce. LDS ~59 KB -> 2 blocks/CU.
// ---------------------------------------------------------------------------
__global__ __launch_bounds__(256) void xreadproj_kernel(
    const float* __restrict__ x,
    float* __restrict__ pool16, float* __restrict__ xp16o,
    float* __restrict__ xp8o, float* __restrict__ xp4o,
    float* __restrict__ sx) {

    __shared__ float BU16[16][66], BS16[16][66];
    __shared__ float BU8[16][68],  BS8[16][68];
    __shared__ float BU4[16][72],  BS4[16][72];
    __shared__ float P0[16][64];
    __shared__ float Rl[256 * 29];      // rowproj, padded stride 29
    __shared__ float rs[4][2];

    int bc = blockIdx.x;
    int t = threadIdx.x;
    int wg = t >> 6, l = t & 63;

    const float4* xp = (const float4*)(x + (size_t)bc * (H * Wd));

    // guard zeros (persist across slabs; per-slab stores never touch them)
    for (int e = t; e < 448; e += 256) {
        int r = e / 28, g = e - r * 28;
        if (g < 2)       BU16[r][64 + g] = 0.f;
        else if (g < 4)  BS16[r][g - 2] = 0.f;
        else if (g < 8)  BU8[r][64 + (g - 4)] = 0.f;
        else if (g < 12) BS8[r][g - 8] = 0.f;
        else if (g < 20) BU4[r][64 + (g - 12)] = 0.f;
        else             BS4[r][g - 20] = 0.f;
    }

    // per-lane w-side constants (validated)
    float a16, b16, a8, b8, a4, b4;
    {
        float w0 = 4.f * (float)l + 0.5f;
        float s16v = w0 * 0.0625f - 0.5f;
        if (l <= 1 || l >= 62) { a16 = 0.f; b16 = 0.f; }
        else { a16 = s16v - floorf(s16v); b16 = 0.0625f; }
        float s8v = w0 * 0.03125f - 0.5f;
        if (l <= 3 || l >= 60) { a8 = 0.f; b8 = 0.f; }
        else { a8 = s8v - floorf(s8v); b8 = 0.03125f; }
        float s4v = w0 * 0.015625f - 0.5f;
        if (l <= 7 || l >= 56) { a4 = 0.f; b4 = 0.f; }
        else { a4 = s4v - floorf(s4v); b4 = 0.015625f; }
    }

    float sx1 = 0.f, sx2 = 0.f;
    float4 v[4], vn[4];
#pragma unroll
    for (int it = 0; it < 4; ++it)
        v[it] = xp[(wg * 4 + it) * 64 + l];

#pragma unroll 1
    for (int slab = 0; slab < 16; ++slab) {
        // stage current slab to guarded LDS + accumulate sx
#pragma unroll
        for (int it = 0; it < 4; ++it) {
            int r = wg * 4 + it;
            float4 vv = v[it];
            float p0 = (vv.x + vv.y) + (vv.z + vv.w);
            float pw = fmaf(3.f, vv.w, fmaf(2.f, vv.z, vv.y));
            sx1 += p0;
            sx2 += vv.x * vv.x + vv.y * vv.y + vv.z * vv.z + vv.w * vv.w;
            float S16 = fmaf(b16, pw, a16 * p0);
            float S8  = fmaf(b8,  pw, a8  * p0);
            float S4  = fmaf(b4,  pw, a4  * p0);
            BU16[r][l] = p0 - S16;  BS16[r][2 + l] = S16;
            BU8[r][l]  = p0 - S8;   BS8[r][4 + l]  = S8;
            BU4[r][l]  = p0 - S4;   BS4[r][8 + l]  = S4;
            P0[r][l] = p0;
        }
        __syncthreads();                    // (A) stores visible

        // prefetch next slab to registers (stays in flight through merge)
        if (slab < 15) {
#pragma unroll
            for (int it = 0; it < 4; ++it)
                vn[it] = xp[((slab + 1) * 16 + wg * 4 + it) * 64 + l];
        }

        // static-count column-reduce (validated round 6), R -> LDS
        int rbase = slab * 16;
        for (int tk = t; tk < 464; tk += 256) {
            if (tk < 256) {                       // s16
                int r = tk >> 4, j = tk & 15;
                float sum = 0.f;
#pragma unroll
                for (int k = 0; k < 4; ++k) sum += BU16[r][4 * j + 2 + k];
#pragma unroll
                for (int k = 0; k < 4; ++k) sum += BS16[r][4 * j + k];
                if (j == 0) sum += BU16[r][0] + BU16[r][1];
                Rl[(rbase + r) * 29 + j] = sum;
            } else if (tk < 384) {                // s8
                int q = tk - 256; int r = q >> 3, j = q & 7;
                float sum = 0.f;
#pragma unroll
                for (int k = 0; k < 8; ++k) sum += BU8[r][8 * j + 4 + k];
#pragma unroll
                for (int k = 0; k < 8; ++k) sum += BS8[r][8 * j + k];
                if (j == 0) sum += BU8[r][0] + BU8[r][1] + BU8[r][2] + BU8[r][3];
                Rl[(rbase + r) * 29 + 16 + j] = sum;
            } else if (tk < 448) {                // s4
                int q = tk - 384; int r = q >> 2, j = q & 3;
                float sum = 0.f;
#pragma unroll
                for (int k = 0; k < 16; ++k) sum += BU4[r][16 * j + 8 + k];
#pragma unroll
                for (int k = 0; k < 16; ++k) sum += BS4[r][16 * j + k];
                if (j == 0) {
#pragma unroll
                    for (int k = 0; k < 8; ++k) sum += BU4[r][k];
                }
                Rl[(rbase + r) * 29 + 24 + j] = sum;
            } else {                              // pool row
                int j = tk - 448;
                float sum = 0.f;
#pragma unroll
                for (int r2 = 0; r2 < 16; ++r2) {
#pragma unroll
                    for (int k = 0; k < 4; ++k) sum += P0[r2][4 * j + k];
                }
                pool16[(size_t)bc * 256 + rbase + j] = sum * (1.f / 256.f);
            }
        }
        __syncthreads();                    // (B) merge reads done
#pragma unroll
        for (int it = 0; it < 4; ++it) v[it] = vn[it];
    }

    // ---- h-fold tail (validated proj_kernel loops, on LDS-resident Rl) ----
    {
        int i = t >> 4, j = t & 15;
        float acc = 0.f;
        int r0 = max(0, 16 * i - 8), r1 = min(255, 16 * i + 23);
        for (int r = r0; r <= r1; ++r) {
            float src = fminf(fmaxf(((float)r + 0.5f) * 0.0625f - 0.5f, 0.f), 15.f);
            int lo = (int)src; float fr = src - (float)lo;
            float w = (i == lo) ? (1.f - fr) : ((i == lo + 1) ? fr : 0.f);
            acc += w * Rl[r * 29 + j];
        }
        xp16o[(size_t)bc * 256 + t] = acc;
    }
    if (t < 64) {
        int i = t >> 3, j = t & 7;
        float acc = 0.f;
        int r0 = max(0, 32 * i - 16), r1 = min(255, 32 * i + 47);
        for (int r = r0; r <= r1; ++r) {
            float src = fminf(fmaxf(((float)r + 0.5f) * 0.03125f - 0.5f, 0.f), 7.f);
            int lo = (int)src; float fr = src - (float)lo;
            float w = (i == lo) ? (1.f - fr) : ((i == lo + 1) ? fr : 0.f);
            acc += w * Rl[r * 29 + 16 + j];
        }
        xp8o[(size_t)bc * 64 + t] = acc;
    } else if (t < 80) {
        int e = t - 64;
        int i = e >> 2, j = e & 3;
        float acc = 0.f;
        int r0 = max(0, 64 * i - 32), r1 = min(255, 64 * i + 95);
        for (int r = r0; r <= r1; ++r) {
            float src = fminf(fmaxf(((float)r + 0.5f) * 0.015625f - 0.5f, 0.f), 3.f);
            int lo = (int)src; float fr = src - (float)lo;
            float w = (i == lo) ? (1.f - fr) : ((i == lo + 1) ? fr : 0.f);
            acc += w * Rl[r * 29 + 24 + j];
        }
        xp4o[(size_t)bc * 16 + e] = acc;
    }

    // sx: per-thread accumulators -> wave reduce (validated pattern)
#pragma unroll
    for (int off = 1; off < 64; off <<= 1) {
        sx1 += __shfl_xor(sx1, off);
        sx2 += __shfl_xor(sx2, off);
    }
    if (l == 0) { rs[wg][0] = sx1; rs[wg][1] = sx2; }
    __syncthreads();
    if (t == 0) {
        sx[bc * 2]     = rs[0][0] + rs[1][0] + rs[2][0] + rs[3][0];
        sx[bc * 2 + 1] = rs[0][1] + rs[1][1] + rs[2][1] + rs[3][1];
    }
}

// ---------------------------------------------------------------------------
// K2: per (b, scale, site) attention + channel-mix. (unchanged, validated)
// ---------------------------------------------------------------------------
__global__ __launch_bounds__(256) void site_kernel(
    const float* __restrict__ pool16,
    const float* __restrict__ cw0, const float* __restrict__ cw1,
    const float* __restrict__ cw2,
    const float* __restrict__ sw0, const float* __restrict__ sw1,
    const float* __restrict__ sw2,
    const float* __restrict__ fusion_w,
    float* __restrict__ y4, float* __restrict__ y8, float* __restrict__ y16) {

    __shared__ float P[256];
    __shared__ float Wm[961];
    __shared__ float QKV[279];
    __shared__ float QW[93];
    __shared__ float A[9];
    __shared__ float OUTV[93];

    int t = threadIdx.x;
    int blk = blockIdx.x;
    int b = blk / 336;
    int r = blk % 336;

    int s, site, foff;
    const float* cw; const float* sw; float* yout;
    if (r < 256)      { s = 16; site = r;       cw = cw2; sw = sw2; foff = 186; yout = y16; }
    else if (r < 320) { s = 8;  site = r - 256; cw = cw1; sw = sw1; foff = 93;  yout = y8;  }
    else              { s = 4;  site = r - 320; cw = cw0; sw = sw0; foff = 0;   yout = y4;  }
    int i = site / s, j = site % s;

    for (int idx = t; idx < 961; idx += 256) Wm[idx] = sw[idx];

    {
        int f = 16 / s;
        float acc = 0.f;
        int base = (b * 256 + t) * 256;
        for (int ii = 0; ii < f; ++ii)
            for (int jj = 0; jj < f; ++jj)
                acc += pool16[base + (i * f + ii) * 16 + (j * f + jj)];
        P[t] = acc / (float)(f * f);
    }
    __syncthreads();

    for (int o = t; o < 279; o += 256) {
        const float4* wrow = (const float4*)(cw + o * 256);
        float acc = 0.f;
#pragma unroll 8
        for (int c4 = 0; c4 < 64; ++c4) {
            float4 wv = wrow[c4];
            acc += wv.x * P[c4 * 4] + wv.y * P[c4 * 4 + 1] +
                   wv.z * P[c4 * 4 + 2] + wv.w * P[c4 * 4 + 3];
        }
        QKV[o] = acc;
    }
    __syncthreads();

    if (t < 93) {
        int g = t / 31, m = t % 31;
        float acc = 0.f;
        for (int n = 0; n < 31; ++n) acc += QKV[g * 31 + n] * Wm[n * 31 + m];
        QW[t] = acc;
    }
    __syncthreads();
    if (t < 9) {
        int g = t / 3, h = t % 3;
        float acc = 0.f;
        for (int m = 0; m < 31; ++m) acc += QW[g * 31 + m] * QKV[93 + h * 31 + m];
        A[t] = acc * 0.57735026918962576f;
    }
    __syncthreads();
    if (t < 3) {
        float a0 = A[t * 3], a1 = A[t * 3 + 1], a2 = A[t * 3 + 2];
        float mx = fmaxf(a0, fmaxf(a1, a2));
        float e0 = expf(a0 - mx), e1 = expf(a1 - mx), e2 = expf(a2 - mx);
        float inv = 1.0f / (e0 + e1 + e2);
        A[t * 3] = e0 * inv; A[t * 3 + 1] = e1 * inv; A[t * 3 + 2] = e2 * inv;
    }
    __syncthreads();
    if (t < 93) {
        int g = t / 31, n = t % 31;
        OUTV[t] = A[g * 3] * QKV[186 + n] + A[g * 3 + 1] * QKV[186 + 31 + n] +
                  A[g * 3 + 2] * QKV[186 + 62 + n];
    }
    __syncthreads();
    {
        const float* fr = fusion_w + t * 279 + foff;
        float acc = 0.f;
#pragma unroll 31
        for (int c = 0; c < 93; ++c) acc += fr[c] * OUTV[c];
        yout[(size_t)(b * 256 + t) * (s * s) + site] = acc;
    }
}

// ---------------------------------------------------------------------------
// K3: GroupNorm stats WITHOUT touching x. (unchanged, validated)
// ---------------------------------------------------------------------------
__global__ __launch_bounds__(256) void groupstats_kernel(
    const float* __restrict__ y4, const float* __restrict__ y8,
    const float* __restrict__ y16,
    const float* __restrict__ xp4, const float* __restrict__ xp8,
    const float* __restrict__ xp16,
    const float* __restrict__ sx, const float* __restrict__ fusion_b,
    float* __restrict__ stats_g) {

    __shared__ float G1616[256], G168[128], G164[64], G88[64], G84[32], G44[16];
    __shared__ float cs[28];
    __shared__ float ybuf[336], xbuf[336];
    __shared__ float Tm[256];
    __shared__ float red[8];

    int t = threadIdx.x;
    int bg = blockIdx.x;
    int b = bg >> 5, g = bg & 31;

    for (int e = t; e < 588; e += 256) {
        if (e >= 560) {
            int q = e - 560; int sC, iC;
            if (q < 16) { sC = 16; iC = q; }
            else if (q < 24) { sC = 8; iC = q - 16; }
            else { sC = 4; iC = q - 24; }
            int R = 256 / sC;
            int lo = max(0, R * iC - R / 2), hi = min(256, R * iC + (3 * R) / 2);
            float Rinv = 1.f / (float)R, smax = (float)(sC - 1);
            float a = 0.f;
            for (int h = lo; h < hi; ++h) {
                float src = fminf(fmaxf(((float)h + 0.5f) * Rinv - 0.5f, 0.f), smax);
                int lq = (int)src; float fr = src - (float)lq;
                a += (iC == lq) ? (1.f - fr) : ((iC == lq + 1) ? fr : 0.f);
            }
            cs[q] = a;
            continue;
        }
        int sA, sB, iA, iB; float* dst; int off;
        if (e < 256)      { sA = 16; sB = 16; iA = e >> 4; iB = e & 15; dst = G1616; off = e; }
        else if (e < 384) { int q = e - 256; sA = 16; sB = 8; iA = q >> 3; iB = q & 7; dst = G168; off = q; }
        else if (e < 448) { int q = e - 384; sA = 16; sB = 4; iA = q >> 2; iB = q & 3; dst = G164; off = q; }
        else if (e < 512) { int q = e - 448; sA = 8;  sB = 8; iA = q >> 3; iB = q & 7; dst = G88;  off = q; }
        else if (e < 544) { int q = e - 512; sA = 8;  sB = 4; iA = q >> 2; iB = q & 3; dst = G84;  off = q; }
        else              { int q = e - 544; sA = 4;  sB = 4; iA = q >> 2; iB = q & 3; dst = G44;  off = q; }
        int RA = 256 / sA, RB = 256 / sB;
        int lo = max(max(0, RA * iA - RA / 2), RB * iB - RB / 2);
        int hi = min(min(256, RA * iA + (3 * RA) / 2), RB * iB + (3 * RB) / 2);
        float RAi = 1.f / (float)RA, RBi = 1.f / (float)RB;
        float smA = (float)(sA - 1), smB = (float)(sB - 1);
        float a = 0.f;
        for (int h = lo; h < hi; ++h) {
            float sa = fminf(fmaxf(((float)h + 0.5f) * RAi - 0.5f, 0.f), smA);
            int la = (int)sa; float fa = sa - (float)la;
            float wa = (iA == la) ? (1.f - fa) : ((iA == la + 1) ? fa : 0.f);
            float sb = fminf(fmaxf(((float)h + 0.5f) * RBi - 0.5f, 0.f), smB);
            int lb = (int)sb; float fb_ = sb - (float)lb;
            float wb = (iB == lb) ? (1.f - fb_) : ((iB == lb + 1) ? fb_ : 0.f);
            a += wa * wb;
        }
        dst[off] = a;
    }
    __syncthreads();

    double gS1 = 0.0, gS2 = 0.0;

    for (int c8 = 0; c8 < 8; ++c8) {
        int c = g * 8 + c8;
        size_t bc = (size_t)(b * 256 + c);
        ybuf[t] = y16[bc * 256 + t];
        xbuf[t] = xp16[bc * 256 + t];
        if (t < 64) { ybuf[256 + t] = y8[bc * 64 + t]; xbuf[256 + t] = xp8[bc * 64 + t]; }
        else if (t < 80) { ybuf[256 + t] = y4[bc * 16 + (t - 64)]; xbuf[256 + t] = xp4[bc * 16 + (t - 64)]; }
        __syncthreads();

        float pu = 0.f, pv = 0.f;
        for (int e = t; e < 336; e += 256) {
            float yv = ybuf[e];
            pv += 2.f * yv * xbuf[e];
            int ci, cj;
            if (e < 256)      { ci = e >> 4;               cj = e & 15; }
            else if (e < 320) { ci = 16 + ((e - 256) >> 3); cj = 16 + ((e - 256) & 7); }
            else              { ci = 24 + ((e - 320) >> 2); cj = 24 + ((e - 320) & 3); }
            pu += yv * cs[ci] * cs[cj];
        }

        for (int p = 0; p < 6; ++p) {
            const float* Gp; int sA, sB, yAoff, yBoff; float factor;
            switch (p) {
                case 0: Gp = G1616; sA = 16; sB = 16; yAoff = 0;   yBoff = 0;   factor = 1.f; break;
                case 1: Gp = G168;  sA = 16; sB = 8;  yAoff = 0;   yBoff = 256; factor = 2.f; break;
                case 2: Gp = G164;  sA = 16; sB = 4;  yAoff = 0;   yBoff = 320; factor = 2.f; break;
                case 3: Gp = G88;   sA = 8;  sB = 8;  yAoff = 256; yBoff = 256; factor = 1.f; break;
                case 4: Gp = G84;   sA = 8;  sB = 4;  yAoff = 256; yBoff = 320; factor = 2.f; break;
                default:Gp = G44;   sA = 4;  sB = 4;  yAoff = 320; yBoff = 320; factor = 1.f; break;
            }
            __syncthreads();
            int nT = sB * sA;
            if (t < nT) {
                int iB = t / sA, jA = t - iB * sA;
                float a = 0.f;
                for (int jB = 0; jB < sB; ++jB)
                    a += Gp[jA * sB + jB] * ybuf[yBoff + iB * sB + jB];
                Tm[t] = a;
            }
            __syncthreads();
            int nB = sA * sA;
            if (t < nB) {
                int iA = t / sA, jA = t - iA * sA;
                float a = 0.f;
                for (int iB = 0; iB < sB; ++iB)
                    a += Gp[iA * sB + iB] * Tm[iB * sA + jA];
                pv += factor * ybuf[yAoff + t] * a;
            }
        }

#pragma unroll
        for (int off = 1; off < 64; off <<= 1) {
            pu += __shfl_xor(pu, off);
            pv += __shfl_xor(pv, off);
        }
        __syncthreads();
        if ((t & 63) == 0) { red[(t >> 6) * 2] = pu; red[(t >> 6) * 2 + 1] = pv; }
        __syncthreads();
        if (t == 0) {
            float puT = red[0] + red[2] + red[4] + red[6];
            float pvT = red[1] + red[3] + red[5] + red[7];
            float fb = fusion_b[c];
            float s1 = sx[(b * 256 + c) * 2], s2 = sx[(b * 256 + c) * 2 + 1];
            double S1 = (double)s1 + 65536.0 * (double)fb + (double)puT;
            double S2 = (double)s2 + 2.0 * (double)fb * (double)s1 +
                        65536.0 * (double)fb * (double)fb +
                        2.0 * (double)fb * (double)puT + (double)pvT;
            gS1 += S1; gS2 += S2;
        }
        __syncthreads();
    }

    if (t == 0) {
        double mean = gS1 / 524288.0;
        double var  = gS2 / 524288.0 - mean * mean;
        stats_g[bg * 2] = (float)mean;
        stats_g[bg * 2 + 1] = (float)(1.0 / sqrt(var + 1e-5));
    }
}

// ---------------------------------------------------------------------------
// K4: final pass — recompute f via LDS-blended interp, normalize, write.
// (unchanged, validated)
// ---------------------------------------------------------------------------
__global__ __launch_bounds__(256) void write_kernel(
    const float* __restrict__ x,
    const float* __restrict__ ws_y4, const float* __restrict__ ws_y8,
    const float* __restrict__ ws_y16,
    const float* __restrict__ fusion_b,
    const float* __restrict__ gn_w, const float* __restrict__ gn_b,
    const float* __restrict__ stats_g,
    float* __restrict__ out) {

    __shared__ float ly16[256], ly8[64], ly4[16];
    __shared__ float2 rbd16[16][16];
    __shared__ float2 rbd8[16][8];
    __shared__ float2 rbd4[16][4];

    int blk = blockIdx.x;
    int hblk = blk & 15;
    int c = (blk >> 4) & 255;
    int b = blk >> 12;
    int t = threadIdx.x;

    ly16[t] = ws_y16[(size_t)(b * 256 + c) * 256 + t];
    if (t < 64) ly8[t] = ws_y8[(size_t)(b * 256 + c) * 64 + t];
    if (t < 16) ly4[t] = ws_y4[(size_t)(b * 256 + c) * 16 + t];
    __syncthreads();

    for (int idx = t; idx < 448; idx += 256) {
        int r = idx / 28;
        int q = idx - r * 28;
        int h = hblk * 16 + r;
        if (q < 16) {
            float src = (h + 0.5f) * 0.0625f - 0.5f;
            src = fminf(fmaxf(src, 0.f), 15.f);
            int lo = (int)src; float wf = src - lo; int hi = min(lo + 1, 15);
            float rb = (1.f - wf) * ly16[lo * 16 + q] + wf * ly16[hi * 16 + q];
            rbd16[r][q].x = rb;
            if (q > 0) rbd16[r][q - 1].y = rb;
            if (q == 15) rbd16[r][15].y = rb;
        } else if (q < 24) {
            int jj = q - 16;
            float src = (h + 0.5f) * 0.03125f - 0.5f;
            src = fminf(fmaxf(src, 0.f), 7.f);
            int lo = (int)src; float wf = src - lo; int hi = min(lo + 1, 7);
            float rb = (1.f - wf) * ly8[lo * 8 + jj] + wf * ly8[hi * 8 + jj];
            rbd8[r][jj].x = rb;
            if (jj > 0) rbd8[r][jj - 1].y = rb;
            if (jj == 7) rbd8[r][7].y = rb;
        } else {
            int jj = q - 24;
            float src = (h + 0.5f) * 0.015625f - 0.5f;
            src = fminf(fmaxf(src, 0.f), 3.f);
            int lo = (int)src; float wf = src - lo; int hi = min(lo + 1, 3);
            float rb = (1.f - wf) * ly4[lo * 4 + jj] + wf * ly4[hi * 4 + jj];
            rbd4[r][jj].x = rb;
            if (jj > 0) rbd4[r][jj - 1].y = rb;
            if (jj == 3) rbd4[r][3].y = rb;
        }
    }
    __syncthreads();

    int w4 = t & 63;
    int wg = t >> 6;
    int w0 = w4 * 4;

    int jlo16[4], jlo8[4], jlo4[4];
    float ww16[4], ww8[4], ww4[4];
#pragma unroll
    for (int p = 0; p < 4; ++p) {
        int w = w0 + p;
        float s16 = fminf(fmaxf((w + 0.5f) * 0.0625f - 0.5f, 0.f), 15.f);
        jlo16[p] = (int)s16; ww16[p] = s16 - jlo16[p];
        float s8 = fminf(fmaxf((w + 0.5f) * 0.03125f - 0.5f, 0.f), 7.f);
        jlo8[p] = (int)s8; ww8[p] = s8 - jlo8[p];
        float s4 = fminf(fmaxf((w + 0.5f) * 0.015625f - 0.5f, 0.f), 3.f);
        jlo4[p] = (int)s4; ww4[p] = s4 - jlo4[p];
    }

    float fb_c = fusion_b[c];
    int gidx = c >> 3;
    float mean = stats_g[(b * 32 + gidx) * 2];
    float rstd = stats_g[(b * 32 + gidx) * 2 + 1];
    float gwc = gn_w[c], gbc = gn_b[c];

    const float4* xp = (const float4*)(x + (size_t)(b * 256 + c) * (H * Wd));
    float4* op = (float4*)(out + (size_t)(b * 256 + c) * (H * Wd));

#pragma unroll
    for (int it = 0; it < 4; ++it) {
        int r = it * 4 + wg;
        int idx4 = (hblk * 16 + r) * 64 + w4;
        float4 xv = xp[idx4];
        float res[4];
        float px[4] = {xv.x, xv.y, xv.z, xv.w};
#pragma unroll
        for (int p = 0; p < 4; ++p) {
            float f = fb_c;
            float2 v16 = rbd16[r][jlo16[p]];
            f += (1.f - ww16[p]) * v16.x + ww16[p] * v16.y;
            float2 v8 = rbd8[r][jlo8[p]];
            f += (1.f - ww8[p]) * v8.x + ww8[p] * v8.y;
            float2 v4 = rbd4[r][jlo4[p]];
            f += (1.f - ww4[p]) * v4.x + ww4[p] * v4.y;
            float tv = px[p] + f;
            res[p] = (tv - mean) * rstd * gwc + gbc;
        }
        op[idx4] = make_float4(res[0], res[1], res[2], res[3]);
    }
}

// ---------------------------------------------------------------------------
extern "C" void kernel_launch(void* const* d_in, const int* in_sizes, int n_in,
                              void* d_out, int out_size, void* d_ws, size_t ws_size,
                              hipStream_t stream) {
    const float* x   = (const float*)d_in[0];
    const float* cw0 = (const float*)d_in[1];
    const float* cw1 = (const float*)d_in[2];
    const float* cw2 = (const float*)d_in[3];
    const float* sw0 = (const float*)d_in[4];
    const float* sw1 = (const float*)d_in[5];
    const float* sw2 = (const float*)d_in[6];
    const float* fw  = (const float*)d_in[7];
    const float* fb  = (const float*)d_in[8];
    const float* gw  = (const float*)d_in[9];
    const float* gb  = (const float*)d_in[10];
    float* out = (float*)d_out;

    float* ws     = (float*)d_ws;
    float* pool16 = ws;                    // 262144
    float* y4     = pool16 + 262144;       // 16384
    float* y8     = y4 + 16384;            // 65536
    float* y16    = y8 + 65536;            // 262144
    float* xp16   = y16 + 262144;          // 262144
    float* xp8    = xp16 + 262144;         // 65536
    float* xp4    = xp8 + 65536;           // 16384
    float* sx     = xp4 + 16384;           // 2048
    float* statsg = sx + 2048;             // 256

    xreadproj_kernel<<<B * C, 256, 0, stream>>>(x, pool16, xp16, xp8, xp4, sx);
    site_kernel<<<B * 336, 256, 0, stream>>>(pool16, cw0, cw1, cw2,
                                             sw0, sw1, sw2, fw, y4, y8, y16);
    groupstats_kernel<<<B * 32, 256, 0, stream>>>(y4, y8, y16, xp4, xp8, xp16,
                                                  sx, fb, statsg);
    write_kernel<<<B * C * 16, 256, 0, stream>>>(x, y4, y8, y16, fb, gw, gb,
                                                 statsg, out);
}

// Round 8
// 265.571 us; speedup vs baseline: 1.4977x; 1.0470x over previous
//
#include <hip/hip_runtime.h>
#include <hip/hip_bf16.h>
#include <math.h>

#define B 4
#define C 256
#define H 256
#define Wd 256

// ---------------------------------------------------------------------------
// K1: plane-per-block streaming pass over x (1024 blocks), low-LDS version.
// LDS ~21 KB -> 7 blocks/CU (was 60 KB -> 2 blocks/CU, latency-bound).
//  - staging: P0 + S-arrays only; u = p0 - S recomputed in merge (same
//    operands/order as validated BU reads -> identical values).
//  - R kept only per-slab (R_slab[16][29]); folded into xproj accumulators
//    incrementally. In-window terms = same ascending-r sequence as the
//    validated tail; out-of-window terms are exact +0.0f.
// Schedule/slab: {fold(k-1) | stage(k) | prefetch(k+1)->regs} bar merge(k) bar
// ---------------------------------------------------------------------------
__global__ __launch_bounds__(256) void xreadproj_kernel(
    const float* __restrict__ x,
    float* __restrict__ pool16, float* __restrict__ xp16o,
    float* __restrict__ xp8o, float* __restrict__ xp4o,
    float* __restrict__ sx) {

    __shared__ float P0[16][72];    // p0; guards [64..71]=0
    __shared__ float SS16[16][68];  // [2+l]=S16; guards [0..1],[66..67]=0
    __shared__ float SS8[16][72];   // [4+l]=S8;  guards [0..3],[68..71]=0
    __shared__ float SS4[16][80];   // [8+l]=S4;  guards [0..7],[72..79]=0
    __shared__ float Rs[16 * 29];   // per-slab rowproj, padded stride 29
    __shared__ float rs[4][2];

    int bc = blockIdx.x;
    int t = threadIdx.x;
    int wg = t >> 6, l = t & 63;

    const float4* xp = (const float4*)(x + (size_t)bc * (H * Wd));

    // guard zeros (36 per row; persist across slabs)
    for (int e = t; e < 576; e += 256) {
        int r = e / 36, g = e - r * 36;
        if (g < 8)       P0[r][64 + g] = 0.f;
        else if (g < 10) SS16[r][g - 8] = 0.f;
        else if (g < 12) SS16[r][56 + g] = 0.f;        // 66,67
        else if (g < 16) SS8[r][g - 12] = 0.f;
        else if (g < 20) SS8[r][52 + g] = 0.f;         // 68..71
        else if (g < 28) SS4[r][g - 20] = 0.f;
        else             SS4[r][44 + g] = 0.f;         // 72..79
    }

    // per-lane w-side constants (validated)
    float a16, b16, a8, b8, a4, b4;
    {
        float w0 = 4.f * (float)l + 0.5f;
        float s16v = w0 * 0.0625f - 0.5f;
        if (l <= 1 || l >= 62) { a16 = 0.f; b16 = 0.f; }
        else { a16 = s16v - floorf(s16v); b16 = 0.0625f; }
        float s8v = w0 * 0.03125f - 0.5f;
        if (l <= 3 || l >= 60) { a8 = 0.f; b8 = 0.f; }
        else { a8 = s8v - floorf(s8v); b8 = 0.03125f; }
        float s4v = w0 * 0.015625f - 0.5f;
        if (l <= 7 || l >= 56) { a4 = 0.f; b4 = 0.f; }
        else { a4 = s4v - floorf(s4v); b4 = 0.015625f; }
    }

    // fold-owner indices
    const int i16 = t >> 4, j16 = t & 15;
    const int i8 = t >> 3, j8 = t & 7;              // valid for t<64
    const int i4 = (t - 64) >> 2, j4 = (t - 64) & 3; // valid for 64<=t<80

    float accA = 0.f;   // xp16 entry
    float accB = 0.f;   // xp8 (t<64) or xp4 (64<=t<80)
    float sx1 = 0.f, sx2 = 0.f;

    float4 v[4], vn[4];
#pragma unroll
    for (int it = 0; it < 4; ++it)
        v[it] = xp[(wg * 4 + it) * 64 + l];

#pragma unroll 1
    for (int k = 0; k < 16; ++k) {
        // ---- fold slab k-1 from Rs (validated windows; ascending r) ----
        if (k > 0) {
            int kk = k - 1;
            if (kk >= i16 - 1 && kk <= i16 + 1) {
#pragma unroll
                for (int rl = 0; rl < 16; ++rl) {
                    float src = ((float)(kk * 16 + rl) + 0.5f) * 0.0625f - 0.5f;
                    src = fminf(fmaxf(src, 0.f), 15.f);
                    int lo = (int)src; float fr = src - (float)lo;
                    float w = (i16 == lo) ? (1.f - fr) : ((i16 == lo + 1) ? fr : 0.f);
                    accA += w * Rs[rl * 29 + j16];
                }
            }
            if (t < 64) {
                if (kk >= 2 * i8 - 1 && kk <= 2 * i8 + 2) {
#pragma unroll
                    for (int rl = 0; rl < 16; ++rl) {
                        float src = ((float)(kk * 16 + rl) + 0.5f) * 0.03125f - 0.5f;
                        src = fminf(fmaxf(src, 0.f), 7.f);
                        int lo = (int)src; float fr = src - (float)lo;
                        float w = (i8 == lo) ? (1.f - fr) : ((i8 == lo + 1) ? fr : 0.f);
                        accB += w * Rs[rl * 29 + 16 + j8];
                    }
                }
            } else if (t < 80) {
                if (kk >= 4 * i4 - 2 && kk <= 4 * i4 + 5) {
#pragma unroll
                    for (int rl = 0; rl < 16; ++rl) {
                        float src = ((float)(kk * 16 + rl) + 0.5f) * 0.015625f - 0.5f;
                        src = fminf(fmaxf(src, 0.f), 3.f);
                        int lo = (int)src; float fr = src - (float)lo;
                        float w = (i4 == lo) ? (1.f - fr) : ((i4 == lo + 1) ? fr : 0.f);
                        accB += w * Rs[rl * 29 + 24 + j4];
                    }
                }
            }
        }

        // ---- stage slab k (P0/S only) + sx ----
#pragma unroll
        for (int it = 0; it < 4; ++it) {
            int r = wg * 4 + it;
            float4 vv = v[it];
            float p0 = (vv.x + vv.y) + (vv.z + vv.w);
            float pw = fmaf(3.f, vv.w, fmaf(2.f, vv.z, vv.y));
            sx1 += p0;
            sx2 += vv.x * vv.x + vv.y * vv.y + vv.z * vv.z + vv.w * vv.w;
            P0[r][l]       = p0;
            SS16[r][2 + l] = fmaf(b16, pw, a16 * p0);
            SS8[r][4 + l]  = fmaf(b8,  pw, a8  * p0);
            SS4[r][8 + l]  = fmaf(b4,  pw, a4  * p0);
        }

        // ---- prefetch slab k+1 to registers ----
        if (k < 15) {
#pragma unroll
            for (int it = 0; it < 4; ++it)
                vn[it] = xp[((k + 1) * 16 + wg * 4 + it) * 64 + l];
        }
        __syncthreads();

        // ---- merge slab k: staging -> Rs + pool16 (validated sums) ----
        for (int tk = t; tk < 464; tk += 256) {
            if (tk < 256) {                       // s16
                int r = tk >> 4, j = tk & 15;
                float sum = 0.f;
#pragma unroll
                for (int q = 0; q < 4; ++q)
                    sum += P0[r][4 * j + 2 + q] - SS16[r][4 * j + 4 + q];
#pragma unroll
                for (int q = 0; q < 4; ++q) sum += SS16[r][4 * j + q];
                if (j == 0) sum += (P0[r][0] - SS16[r][2]) + (P0[r][1] - SS16[r][3]);
                Rs[r * 29 + j] = sum;
            } else if (tk < 384) {                // s8
                int q2 = tk - 256; int r = q2 >> 3, j = q2 & 7;
                float sum = 0.f;
#pragma unroll
                for (int q = 0; q < 8; ++q)
                    sum += P0[r][8 * j + 4 + q] - SS8[r][8 * j + 8 + q];
#pragma unroll
                for (int q = 0; q < 8; ++q) sum += SS8[r][8 * j + q];
                if (j == 0) {
#pragma unroll
                    for (int q = 0; q < 4; ++q) sum += P0[r][q] - SS8[r][4 + q];
                }
                Rs[r * 29 + 16 + j] = sum;
            } else if (tk < 448) {                // s4
                int q2 = tk - 384; int r = q2 >> 2, j = q2 & 3;
                float sum = 0.f;
#pragma unroll
                for (int q = 0; q < 16; ++q)
                    sum += P0[r][16 * j + 8 + q] - SS4[r][16 * j + 16 + q];
#pragma unroll
                for (int q = 0; q < 16; ++q) sum += SS4[r][16 * j + q];
                if (j == 0) {
#pragma unroll
                    for (int q = 0; q < 8; ++q) sum += P0[r][q] - SS4[r][8 + q];
                }
                Rs[r * 29 + 24 + j] = sum;
            } else {                              // pool row
                int j = tk - 448;
                float sum = 0.f;
#pragma unroll
                for (int r2 = 0; r2 < 16; ++r2) {
#pragma unroll
                    for (int q = 0; q < 4; ++q) sum += P0[r2][4 * j + q];
                }
                pool16[(size_t)bc * 256 + k * 16 + j] = sum * (1.f / 256.f);
            }
        }
        __syncthreads();
#pragma unroll
        for (int it = 0; it < 4; ++it) v[it] = vn[it];
    }

    // ---- fold last slab (15) ----
    {
        int kk = 15;
        if (kk >= i16 - 1 && kk <= i16 + 1) {
#pragma unroll
            for (int rl = 0; rl < 16; ++rl) {
                float src = ((float)(kk * 16 + rl) + 0.5f) * 0.0625f - 0.5f;
                src = fminf(fmaxf(src, 0.f), 15.f);
                int lo = (int)src; float fr = src - (float)lo;
                float w = (i16 == lo) ? (1.f - fr) : ((i16 == lo + 1) ? fr : 0.f);
                accA += w * Rs[rl * 29 + j16];
            }
        }
        if (t < 64) {
            if (kk >= 2 * i8 - 1 && kk <= 2 * i8 + 2) {
#pragma unroll
                for (int rl = 0; rl < 16; ++rl) {
                    float src = ((float)(kk * 16 + rl) + 0.5f) * 0.03125f - 0.5f;
                    src = fminf(fmaxf(src, 0.f), 7.f);
                    int lo = (int)src; float fr = src - (float)lo;
                    float w = (i8 == lo) ? (1.f - fr) : ((i8 == lo + 1) ? fr : 0.f);
                    accB += w * Rs[rl * 29 + 16 + j8];
                }
            }
        } else if (t < 80) {
            if (kk >= 4 * i4 - 2 && kk <= 4 * i4 + 5) {
#pragma unroll
                for (int rl = 0; rl < 16; ++rl) {
                    float src = ((float)(kk * 16 + rl) + 0.5f) * 0.015625f - 0.5f;
                    src = fminf(fmaxf(src, 0.f), 3.f);
                    int lo = (int)src; float fr = src - (float)lo;
                    float w = (i4 == lo) ? (1.f - fr) : ((i4 == lo + 1) ? fr : 0.f);
                    accB += w * Rs[rl * 29 + 24 + j4];
                }
            }
        }
    }

    xp16o[(size_t)bc * 256 + t] = accA;
    if (t < 64) xp8o[(size_t)bc * 64 + t] = accB;
    else if (t < 80) xp4o[(size_t)bc * 16 + (t - 64)] = accB;

    // sx: wave reduce (validated pattern)
#pragma unroll
    for (int off = 1; off < 64; off <<= 1) {
        sx1 += __shfl_xor(sx1, off);
        sx2 += __shfl_xor(sx2, off);
    }
    if (l == 0) { rs[wg][0] = sx1; rs[wg][1] = sx2; }
    __syncthreads();
    if (t == 0) {
        sx[bc * 2]     = rs[0][0] + rs[1][0] + rs[2][0] + rs[3][0];
        sx[bc * 2 + 1] = rs[0][1] + rs[1][1] + rs[2][1] + rs[3][1];
    }
}

// ---------------------------------------------------------------------------
// K2: per (b, scale, site) attention + channel-mix. (unchanged, validated)
// ---------------------------------------------------------------------------
__global__ __launch_bounds__(256) void site_kernel(
    const float* __restrict__ pool16,
    const float* __restrict__ cw0, const float* __restrict__ cw1,
    const float* __restrict__ cw2,
    const float* __restrict__ sw0, const float* __restrict__ sw1,
    const float* __restrict__ sw2,
    const float* __restrict__ fusion_w,
    float* __restrict__ y4, float* __restrict__ y8, float* __restrict__ y16) {

    __shared__ float P[256];
    __shared__ float Wm[961];
    __shared__ float QKV[279];
    __shared__ float QW[93];
    __shared__ float A[9];
    __shared__ float OUTV[93];

    int t = threadIdx.x;
    int blk = blockIdx.x;
    int b = blk / 336;
    int r = blk % 336;

    int s, site, foff;
    const float* cw; const float* sw; float* yout;
    if (r < 256)      { s = 16; site = r;       cw = cw2; sw = sw2; foff = 186; yout = y16; }
    else if (r < 320) { s = 8;  site = r - 256; cw = cw1; sw = sw1; foff = 93;  yout = y8;  }
    else              { s = 4;  site = r - 320; cw = cw0; sw = sw0; foff = 0;   yout = y4;  }
    int i = site / s, j = site % s;

    for (int idx = t; idx < 961; idx += 256) Wm[idx] = sw[idx];

    {
        int f = 16 / s;
        float acc = 0.f;
        int base = (b * 256 + t) * 256;
        for (int ii = 0; ii < f; ++ii)
            for (int jj = 0; jj < f; ++jj)
                acc += pool16[base + (i * f + ii) * 16 + (j * f + jj)];
        P[t] = acc / (float)(f * f);
    }
    __syncthreads();

    for (int o = t; o < 279; o += 256) {
        const float4* wrow = (const float4*)(cw + o * 256);
        float acc = 0.f;
#pragma unroll 8
        for (int c4 = 0; c4 < 64; ++c4) {
            float4 wv = wrow[c4];
            acc += wv.x * P[c4 * 4] + wv.y * P[c4 * 4 + 1] +
                   wv.z * P[c4 * 4 + 2] + wv.w * P[c4 * 4 + 3];
        }
        QKV[o] = acc;
    }
    __syncthreads();

    if (t < 93) {
        int g = t / 31, m = t % 31;
        float acc = 0.f;
        for (int n = 0; n < 31; ++n) acc += QKV[g * 31 + n] * Wm[n * 31 + m];
        QW[t] = acc;
    }
    __syncthreads();
    if (t < 9) {
        int g = t / 3, h = t % 3;
        float acc = 0.f;
        for (int m = 0; m < 31; ++m) acc += QW[g * 31 + m] * QKV[93 + h * 31 + m];
        A[t] = acc * 0.57735026918962576f;
    }
    __syncthreads();
    if (t < 3) {
        float a0 = A[t * 3], a1 = A[t * 3 + 1], a2 = A[t * 3 + 2];
        float mx = fmaxf(a0, fmaxf(a1, a2));
        float e0 = expf(a0 - mx), e1 = expf(a1 - mx), e2 = expf(a2 - mx);
        float inv = 1.0f / (e0 + e1 + e2);
        A[t * 3] = e0 * inv; A[t * 3 + 1] = e1 * inv; A[t * 3 + 2] = e2 * inv;
    }
    __syncthreads();
    if (t < 93) {
        int g = t / 31, n = t % 31;
        OUTV[t] = A[g * 3] * QKV[186 + n] + A[g * 3 + 1] * QKV[186 + 31 + n] +
                  A[g * 3 + 2] * QKV[186 + 62 + n];
    }
    __syncthreads();
    {
        const float* fr = fusion_w + t * 279 + foff;
        float acc = 0.f;
#pragma unroll 31
        for (int c = 0; c < 93; ++c) acc += fr[c] * OUTV[c];
        yout[(size_t)(b * 256 + t) * (s * s) + site] = acc;
    }
}

// ---------------------------------------------------------------------------
// K3: GroupNorm stats WITHOUT touching x. (unchanged, validated)
// ---------------------------------------------------------------------------
__global__ __launch_bounds__(256) void groupstats_kernel(
    const float* __restrict__ y4, const float* __restrict__ y8,
    const float* __restrict__ y16,
    const float* __restrict__ xp4, const float* __restrict__ xp8,
    const float* __restrict__ xp16,
    const float* __restrict__ sx, const float* __restrict__ fusion_b,
    float* __restrict__ stats_g) {

    __shared__ float G1616[256], G168[128], G164[64], G88[64], G84[32], G44[16];
    __shared__ float cs[28];
    __shared__ float ybuf[336], xbuf[336];
    __shared__ float Tm[256];
    __shared__ float red[8];

    int t = threadIdx.x;
    int bg = blockIdx.x;
    int b = bg >> 5, g = bg & 31;

    for (int e = t; e < 588; e += 256) {
        if (e >= 560) {
            int q = e - 560; int sC, iC;
            if (q < 16) { sC = 16; iC = q; }
            else if (q < 24) { sC = 8; iC = q - 16; }
            else { sC = 4; iC = q - 24; }
            int R = 256 / sC;
            int lo = max(0, R * iC - R / 2), hi = min(256, R * iC + (3 * R) / 2);
            float Rinv = 1.f / (float)R, smax = (float)(sC - 1);
            float a = 0.f;
            for (int h = lo; h < hi; ++h) {
                float src = fminf(fmaxf(((float)h + 0.5f) * Rinv - 0.5f, 0.f), smax);
                int lq = (int)src; float fr = src - (float)lq;
                a += (iC == lq) ? (1.f - fr) : ((iC == lq + 1) ? fr : 0.f);
            }
            cs[q] = a;
            continue;
        }
        int sA, sB, iA, iB; float* dst; int off;
        if (e < 256)      { sA = 16; sB = 16; iA = e >> 4; iB = e & 15; dst = G1616; off = e; }
        else if (e < 384) { int q = e - 256; sA = 16; sB = 8; iA = q >> 3; iB = q & 7; dst = G168; off = q; }
        else if (e < 448) { int q = e - 384; sA = 16; sB = 4; iA = q >> 2; iB = q & 3; dst = G164; off = q; }
        else if (e < 512) { int q = e - 448; sA = 8;  sB = 8; iA = q >> 3; iB = q & 7; dst = G88;  off = q; }
        else if (e < 544) { int q = e - 512; sA = 8;  sB = 4; iA = q >> 2; iB = q & 3; dst = G84;  off = q; }
        else              { int q = e - 544; sA = 4;  sB = 4; iA = q >> 2; iB = q & 3; dst = G44;  off = q; }
        int RA = 256 / sA, RB = 256 / sB;
        int lo = max(max(0, RA * iA - RA / 2), RB * iB - RB / 2);
        int hi = min(min(256, RA * iA + (3 * RA) / 2), RB * iB + (3 * RB) / 2);
        float RAi = 1.f / (float)RA, RBi = 1.f / (float)RB;
        float smA = (float)(sA - 1), smB = (float)(sB - 1);
        float a = 0.f;
        for (int h = lo; h < hi; ++h) {
            float sa = fminf(fmaxf(((float)h + 0.5f) * RAi - 0.5f, 0.f), smA);
            int la = (int)sa; float fa = sa - (float)la;
            float wa = (iA == la) ? (1.f - fa) : ((iA == la + 1) ? fa : 0.f);
            float sb = fminf(fmaxf(((float)h + 0.5f) * RBi - 0.5f, 0.f), smB);
            int lb = (int)sb; float fb_ = sb - (float)lb;
            float wb = (iB == lb) ? (1.f - fb_) : ((iB == lb + 1) ? fb_ : 0.f);
            a += wa * wb;
        }
        dst[off] = a;
    }
    __syncthreads();

    double gS1 = 0.0, gS2 = 0.0;

    for (int c8 = 0; c8 < 8; ++c8) {
        int c = g * 8 + c8;
        size_t bc = (size_t)(b * 256 + c);
        ybuf[t] = y16[bc * 256 + t];
        xbuf[t] = xp16[bc * 256 + t];
        if (t < 64) { ybuf[256 + t] = y8[bc * 64 + t]; xbuf[256 + t] = xp8[bc * 64 + t]; }
        else if (t < 80) { ybuf[256 + t] = y4[bc * 16 + (t - 64)]; xbuf[256 + t] = xp4[bc * 16 + (t - 64)]; }
        __syncthreads();

        float pu = 0.f, pv = 0.f;
        for (int e = t; e < 336; e += 256) {
            float yv = ybuf[e];
            pv += 2.f * yv * xbuf[e];
            int ci, cj;
            if (e < 256)      { ci = e >> 4;               cj = e & 15; }
            else if (e < 320) { ci = 16 + ((e - 256) >> 3); cj = 16 + ((e - 256) & 7); }
            else              { ci = 24 + ((e - 320) >> 2); cj = 24 + ((e - 320) & 3); }
            pu += yv * cs[ci] * cs[cj];
        }

        for (int p = 0; p < 6; ++p) {
            const float* Gp; int sA, sB, yAoff, yBoff; float factor;
            switch (p) {
                case 0: Gp = G1616; sA = 16; sB = 16; yAoff = 0;   yBoff = 0;   factor = 1.f; break;
                case 1: Gp = G168;  sA = 16; sB = 8;  yAoff = 0;   yBoff = 256; factor = 2.f; break;
                case 2: Gp = G164;  sA = 16; sB = 4;  yAoff = 0;   yBoff = 320; factor = 2.f; break;
                case 3: Gp = G88;   sA = 8;  sB = 8;  yAoff = 256; yBoff = 256; factor = 1.f; break;
                case 4: Gp = G84;   sA = 8;  sB = 4;  yAoff = 256; yBoff = 320; factor = 2.f; break;
                default:Gp = G44;   sA = 4;  sB = 4;  yAoff = 320; yBoff = 320; factor = 1.f; break;
            }
            __syncthreads();
            int nT = sB * sA;
            if (t < nT) {
                int iB = t / sA, jA = t - iB * sA;
                float a = 0.f;
                for (int jB = 0; jB < sB; ++jB)
                    a += Gp[jA * sB + jB] * ybuf[yBoff + iB * sB + jB];
                Tm[t] = a;
            }
            __syncthreads();
            int nB = sA * sA;
            if (t < nB) {
                int iA = t / sA, jA = t - iA * sA;
                float a = 0.f;
                for (int iB = 0; iB < sB; ++iB)
                    a += Gp[iA * sB + iB] * Tm[iB * sA + jA];
                pv += factor * ybuf[yAoff + t] * a;
            }
        }

#pragma unroll
        for (int off = 1; off < 64; off <<= 1) {
            pu += __shfl_xor(pu, off);
            pv += __shfl_xor(pv, off);
        }
        __syncthreads();
        if ((t & 63) == 0) { red[(t >> 6) * 2] = pu; red[(t >> 6) * 2 + 1] = pv; }
        __syncthreads();
        if (t == 0) {
            float puT = red[0] + red[2] + red[4] + red[6];
            float pvT = red[1] + red[3] + red[5] + red[7];
            float fb = fusion_b[c];
            float s1 = sx[(b * 256 + c) * 2], s2 = sx[(b * 256 + c) * 2 + 1];
            double S1 = (double)s1 + 65536.0 * (double)fb + (double)puT;
            double S2 = (double)s2 + 2.0 * (double)fb * (double)s1 +
                        65536.0 * (double)fb * (double)fb +
                        2.0 * (double)fb * (double)puT + (double)pvT;
            gS1 += S1; gS2 += S2;
        }
        __syncthreads();
    }

    if (t == 0) {
        double mean = gS1 / 524288.0;
        double var  = gS2 / 524288.0 - mean * mean;
        stats_g[bg * 2] = (float)mean;
        stats_g[bg * 2 + 1] = (float)(1.0 / sqrt(var + 1e-5));
    }
}

// ---------------------------------------------------------------------------
// K4: final pass — recompute f via LDS-blended interp, normalize, write.
// (unchanged, validated)
// ---------------------------------------------------------------------------
__global__ __launch_bounds__(256) void write_kernel(
    const float* __restrict__ x,
    const float* __restrict__ ws_y4, const float* __restrict__ ws_y8,
    const float* __restrict__ ws_y16,
    const float* __restrict__ fusion_b,
    const float* __restrict__ gn_w, const float* __restrict__ gn_b,
    const float* __restrict__ stats_g,
    float* __restrict__ out) {

    __shared__ float ly16[256], ly8[64], ly4[16];
    __shared__ float2 rbd16[16][16];
    __shared__ float2 rbd8[16][8];
    __shared__ float2 rbd4[16][4];

    int blk = blockIdx.x;
    int hblk = blk & 15;
    int c = (blk >> 4) & 255;
    int b = blk >> 12;
    int t = threadIdx.x;

    ly16[t] = ws_y16[(size_t)(b * 256 + c) * 256 + t];
    if (t < 64) ly8[t] = ws_y8[(size_t)(b * 256 + c) * 64 + t];
    if (t < 16) ly4[t] = ws_y4[(size_t)(b * 256 + c) * 16 + t];
    __syncthreads();

    for (int idx = t; idx < 448; idx += 256) {
        int r = idx / 28;
        int q = idx - r * 28;
        int h = hblk * 16 + r;
        if (q < 16) {
            float src = (h + 0.5f) * 0.0625f - 0.5f;
            src = fminf(fmaxf(src, 0.f), 15.f);
            int lo = (int)src; float wf = src - lo; int hi = min(lo + 1, 15);
            float rb = (1.f - wf) * ly16[lo * 16 + q] + wf * ly16[hi * 16 + q];
            rbd16[r][q].x = rb;
            if (q > 0) rbd16[r][q - 1].y = rb;
            if (q == 15) rbd16[r][15].y = rb;
        } else if (q < 24) {
            int jj = q - 16;
            float src = (h + 0.5f) * 0.03125f - 0.5f;
            src = fminf(fmaxf(src, 0.f), 7.f);
            int lo = (int)src; float wf = src - lo; int hi = min(lo + 1, 7);
            float rb = (1.f - wf) * ly8[lo * 8 + jj] + wf * ly8[hi * 8 + jj];
            rbd8[r][jj].x = rb;
            if (jj > 0) rbd8[r][jj - 1].y = rb;
            if (jj == 7) rbd8[r][7].y = rb;
        } else {
            int jj = q - 24;
            float src = (h + 0.5f) * 0.015625f - 0.5f;
            src = fminf(fmaxf(src, 0.f), 3.f);
            int lo = (int)src; float wf = src - lo; int hi = min(lo + 1, 3);
            float rb = (1.f - wf) * ly4[lo * 4 + jj] + wf * ly4[hi * 4 + jj];
            rbd4[r][jj].x = rb;
            if (jj > 0) rbd4[r][jj - 1].y = rb;
            if (jj == 3) rbd4[r][3].y = rb;
        }
    }
    __syncthreads();

    int w4 = t & 63;
    int wg = t >> 6;
    int w0 = w4 * 4;

    int jlo16[4], jlo8[4], jlo4[4];
    float ww16[4], ww8[4], ww4[4];
#pragma unroll
    for (int p = 0; p < 4; ++p) {
        int w = w0 + p;
        float s16 = fminf(fmaxf((w + 0.5f) * 0.0625f - 0.5f, 0.f), 15.f);
        jlo16[p] = (int)s16; ww16[p] = s16 - jlo16[p];
        float s8 = fminf(fmaxf((w + 0.5f) * 0.03125f - 0.5f, 0.f), 7.f);
        jlo8[p] = (int)s8; ww8[p] = s8 - jlo8[p];
        float s4 = fminf(fmaxf((w + 0.5f) * 0.015625f - 0.5f, 0.f), 3.f);
        jlo4[p] = (int)s4; ww4[p] = s4 - jlo4[p];
    }

    float fb_c = fusion_b[c];
    int gidx = c >> 3;
    float mean = stats_g[(b * 32 + gidx) * 2];
    float rstd = stats_g[(b * 32 + gidx) * 2 + 1];
    float gwc = gn_w[c], gbc = gn_b[c];

    const float4* xp = (const float4*)(x + (size_t)(b * 256 + c) * (H * Wd));
    float4* op = (float4*)(out + (size_t)(b * 256 + c) * (H * Wd));

#pragma unroll
    for (int it = 0; it < 4; ++it) {
        int r = it * 4 + wg;
        int idx4 = (hblk * 16 + r) * 64 + w4;
        float4 xv = xp[idx4];
        float res[4];
        float px[4] = {xv.x, xv.y, xv.z, xv.w};
#pragma unroll
        for (int p = 0; p < 4; ++p) {
            float f = fb_c;
            float2 v16 = rbd16[r][jlo16[p]];
            f += (1.f - ww16[p]) * v16.x + ww16[p] * v16.y;
            float2 v8 = rbd8[r][jlo8[p]];
            f += (1.f - ww8[p]) * v8.x + ww8[p] * v8.y;
            float2 v4 = rbd4[r][jlo4[p]];
            f += (1.f - ww4[p]) * v4.x + ww4[p] * v4.y;
            float tv = px[p] + f;
            res[p] = (tv - mean) * rstd * gwc + gbc;
        }
        op[idx4] = make_float4(res[0], res[1], res[2], res[3]);
    }
}

// ---------------------------------------------------------------------------
extern "C" void kernel_launch(void* const* d_in, const int* in_sizes, int n_in,
                              void* d_out, int out_size, void* d_ws, size_t ws_size,
                              hipStream_t stream) {
    const float* x   = (const float*)d_in[0];
    const float* cw0 = (const float*)d_in[1];
    const float* cw1 = (const float*)d_in[2];
    const float* cw2 = (const float*)d_in[3];
    const float* sw0 = (const float*)d_in[4];
    const float* sw1 = (const float*)d_in[5];
    const float* sw2 = (const float*)d_in[6];
    const float* fw  = (const float*)d_in[7];
    const float* fb  = (const float*)d_in[8];
    const float* gw  = (const float*)d_in[9];
    const float* gb  = (const float*)d_in[10];
    float* out = (float*)d_out;

    float* ws     = (float*)d_ws;
    float* pool16 = ws;                    // 262144
    float* y4     = pool16 + 262144;       // 16384
    float* y8     = y4 + 16384;            // 65536
    float* y16    = y8 + 65536;            // 262144
    float* xp16   = y16 + 262144;          // 262144
    float* xp8    = xp16 + 262144;         // 65536
    float* xp4    = xp8 + 65536;           // 16384
    float* sx     = xp4 + 16384;           // 2048
    float* statsg = sx + 2048;             // 256

    xreadproj_kernel<<<B * C, 256, 0, stream>>>(x, pool16, xp16, xp8, xp4, sx);
    site_kernel<<<B * 336, 256, 0, stream>>>(pool16, cw0, cw1, cw2,
                                             sw0, sw1, sw2, fw, y4, y8, y16);
    groupstats_kernel<<<B * 32, 256, 0, stream>>>(y4, y8, y16, xp4, xp8, xp16,
                                                  sx, fb, statsg);
    write_kernel<<<B * C * 16, 256, 0, stream>>>(x, y4, y8, y16, fb, gw, gb,
                                                 statsg, out);
}